// Round 8
// baseline (232.608 us; speedup 1.0000x reference)
//
#include <hip/hip_runtime.h>
#include <hip/hip_bf16.h>
#include <math.h>

// ---------------------------------------------------------------------------
// MultiHeadSelfAttention  B=4 N=2048 E=512 H=8 DK=DV=64   (f32 in / f32 out)
// Split-bf16 (hi/lo) MFMA on the attention-critical path.
//
// Reference quirks (verified passing):
//  * qkv.reshape(B,H,N,192) is token-mixing: with GEMM col g:
//    s=g/192, sect=(g%192)/64, d=g%64, n=8a+s (a=row%256, bh=row/256).
//  * y.reshape: y[b,h,n,d] -> yws[bh*256 + (n>>3)][(n&7)*64 + d]
//  * qk / DK**-0.5 == qk * 8.0
//
// R18 post-mortem: swapped-QK^T packed softmax WORKED (84.6->74.3us attn,
// total 225.2). MfmaUtil 38 + VALU 43 + conflicts ~4% = ~85% busy; occupancy
// GRID-CAPPED at 16 waves/CU (4096 waves of work total). attn's remaining
// slack is VALU addressing (runtime buf -> recomputed addresses).
//
// R19 (this round), two independent per-kernel changes:
//  * attn: chunk loop unrolled x2 via macro -> buf compile-time, LDS/global
//    addressing folds to base+immediate. No numeric change.
//  * qkv_gemm (PRECVT): A-fragment REGISTER PREFETCH - load chunk c+1's A
//    frags before the barrier, during chunk c's MFMAs (T14; R13 lesson:
//    synchronous global loads after the barrier expose L2 latency per
//    chunk). +32 VGPR (~120, not binding at 3 waves/SIMD). MFMA order
//    unchanged -> bit-identical.
//  * cvt/vtrans/out_gemm byte-identical.
// ---------------------------------------------------------------------------

typedef __attribute__((ext_vector_type(8))) short bf16x8;
typedef __attribute__((ext_vector_type(4))) float f32x4;

#define MFMA16(a, b, c) __builtin_amdgcn_mfma_f32_16x16x32_bf16((a), (b), (c), 0, 0, 0)

__device__ __forceinline__ ushort f2bf_rne(float f) {
  union { float f; unsigned u; } v; v.f = f;
  return (ushort)((v.u + 0x7fffu + ((v.u >> 16) & 1u)) >> 16);
}
__device__ __forceinline__ float bf2f(ushort h) {
  union { float f; unsigned u; } v; v.u = ((unsigned)h) << 16; return v.f;
}
__device__ __forceinline__ void split2(float f, ushort& hi, ushort& lo) {
  union { float f; unsigned u; } v; v.f = f;
  hi = (ushort)(v.u >> 16);
  union { float f; unsigned u; } r; r.f = f - bf2f(hi);
  lo = (ushort)(r.u >> 16);          // trunc lo: rel err ~2^-16.5, negligible
}

// async global->LDS, 16B per lane; lds ptr must be wave-uniform (HW adds lane*16)
typedef __attribute__((address_space(3))) unsigned int lds_uint;
typedef const __attribute__((address_space(1))) unsigned int glob_uint;
__device__ __forceinline__ void gl_lds16(const ushort* g, short* l) {
  __builtin_amdgcn_global_load_lds((glob_uint*)g, (lds_uint*)l, 16, 0, 0);
}

// ---------------------------------------------------------------------------
// K0 (fused): W_qkv -> wT_hi/lo K-CHUNKED [c16][n1536][ks32] (contiguous 8KB
// per (tn,c) stage tile); W_o -> woT; and if ROOMY, x -> xh/xl bf16 planes.
// ---------------------------------------------------------------------------
template <bool ROOMY>
__global__ __launch_bounds__(256) void cvt_k(const float* __restrict__ wqkv,
                                             const float* __restrict__ wo,
                                             const float* __restrict__ x,
                                             ushort* __restrict__ wT_hi,
                                             ushort* __restrict__ wT_lo,
                                             ushort* __restrict__ woT,
                                             ushort* __restrict__ xh,
                                             ushort* __restrict__ xl)
{
  const int gid = blockIdx.x * 256 + threadIdx.x;
  if (gid < 786432) {
    const int c   = gid / 49152;          // k-chunk 0..15
    const int rem = gid - c * 49152;
    const int n   = rem >> 5;             // 0..1535
    const int k   = c * 32 + (rem & 31);  // 0..511
    ushort hi, lo; split2(wqkv[(size_t)k * 1536 + n], hi, lo);
    wT_hi[gid] = hi; wT_lo[gid] = lo;     // write-contiguous in chunked layout
  } else if (gid < 1048576) {
    const int g = gid - 786432;
    const int n = g >> 9, k = g & 511;
    woT[g] = f2bf_rne(wo[(size_t)k * 512 + n]);
  } else if (ROOMY) {
    const int g = gid - 1048576;        // 1048576 vec4 slots
    float4 v = ((const float4*)x)[g];
    ushort4 hh, ll;
    split2(v.x, hh.x, ll.x); split2(v.y, hh.y, ll.y);
    split2(v.z, hh.z, ll.z); split2(v.w, hh.w, ll.w);
    ((ushort4*)xh)[g] = hh;
    ((ushort4*)xl)[g] = ll;
  }
}

// ---------------------------------------------------------------------------
// K1: qkv GEMM, 128x128 tile/block (4 waves 2x2, wave = 64x64 = 4x4 acc).
// B staged via global_load_lds(16B) from chunked wT (R14, proven).
// R19: PRECVT path register-prefetches A frags for chunk c+1 before the
// barrier (hides L2 latency under chunk c's MFMAs).
// ---------------------------------------------------------------------------
template <bool PRECVT>
__global__ __launch_bounds__(256) void qkv_gemm_k(
    const float* __restrict__ x,
    const ushort* __restrict__ xh, const ushort* __restrict__ xl,
    const ushort* __restrict__ wT_hi, const ushort* __restrict__ wT_lo,
    const float* __restrict__ bqkv,
    ushort* __restrict__ q_hi, ushort* __restrict__ q_lo,
    ushort* __restrict__ k_hi, ushort* __restrict__ k_lo,
    ushort* __restrict__ v_nat)
{
  const int i = blockIdx.x, j = i >> 3;
  const int tmb = (i & 7) * 8 + (j & 7);   // row-strip, XCD-grouped
  const int tn  = j >> 3;                  // col-panel [0,12)
  const int tid = threadIdx.x, lane = tid & 63, w = tid >> 6;
  const int col16 = lane & 15, quad = lane >> 4;
  const int wr = w >> 1, wc = w & 1;

  __shared__ short sbuf[16384];   // 32KB: hi@[buf*4096], lo@[8192+buf*4096]

  // per-thread global src offset within a chunk (bytes: w*2048 + lane*16)
  const int wl   = w * 1024 + lane * 8;    // ushorts
  const int ldsw = w * 1024;               // wave-uniform LDS offset (ushorts)
  const ushort* shp = wT_hi + (size_t)tn * 4096 + wl;
  const ushort* slp = wT_lo + (size_t)tn * 4096 + wl;

  const float*  axf[4];
  const ushort *axh[4], *axl[4];
#pragma unroll
  for (int rt = 0; rt < 4; ++rt) {
    const size_t rowoff = (size_t)(tmb * 128 + wr * 64 + rt * 16 + col16) * 512 + quad * 8;
    axf[rt] = x  + rowoff;
    axh[rt] = xh + rowoff;
    axl[rt] = xl + rowoff;
  }

  f32x4 acc[4][4];
#pragma unroll
  for (int rt = 0; rt < 4; ++rt)
#pragma unroll
    for (int ct = 0; ct < 4; ++ct) acc[rt][ct] = (f32x4){0.f, 0.f, 0.f, 0.f};

  // prologue: stage chunk 0 into buf 0; preload A frags for chunk 0
  gl_lds16(shp,       sbuf + ldsw);
  gl_lds16(shp + 512, sbuf + ldsw + 512);
  gl_lds16(slp,       sbuf + 8192 + ldsw);
  gl_lds16(slp + 512, sbuf + 8192 + ldsw + 512);

  bf16x8 pa_hi[4], pa_lo[4];
  if constexpr (PRECVT) {
#pragma unroll
    for (int rt = 0; rt < 4; ++rt) {
      pa_hi[rt] = *(const bf16x8*)(axh[rt]);
      pa_lo[rt] = *(const bf16x8*)(axl[rt]);
    }
  }
  __syncthreads();

  int buf = 0;
#pragma unroll
  for (int c = 0; c < 16; ++c) {
    if (c < 15) {                        // issue next-chunk B stages (async)
      const size_t co = (size_t)(c + 1) * 49152;
      const int nb = (buf ^ 1) * 4096;
      gl_lds16(shp + co,       sbuf + nb + ldsw);
      gl_lds16(shp + co + 512, sbuf + nb + ldsw + 512);
      gl_lds16(slp + co,       sbuf + 8192 + nb + ldsw);
      gl_lds16(slp + co + 512, sbuf + 8192 + nb + ldsw + 512);
    }
    // prefetch A frags for chunk c+1 (regs) BEFORE MFMAs & barrier
    bf16x8 na_hi[4], na_lo[4];
    if constexpr (PRECVT) {
      if (c < 15) {
        const int kn = (c + 1) * 32;
#pragma unroll
        for (int rt = 0; rt < 4; ++rt) {
          na_hi[rt] = *(const bf16x8*)(axh[rt] + kn);
          na_lo[rt] = *(const bf16x8*)(axl[rt] + kn);
        }
      }
    }
    const int k0 = c * 32;
    const short* bhb = sbuf + buf * 4096;
    const short* blb = sbuf + 8192 + buf * 4096;

    bf16x8 bh[4], bl[4];
#pragma unroll
    for (int ct = 0; ct < 4; ++ct) {
      const int roff = (wc * 64 + ct * 16 + col16) * 32 + quad * 8;
      bh[ct] = *(const bf16x8*)(bhb + roff);
      bl[ct] = *(const bf16x8*)(blb + roff);
    }
#pragma unroll
    for (int rt = 0; rt < 4; ++rt) {
      bf16x8 a_hi, a_lo;
      if constexpr (PRECVT) {
        a_hi = pa_hi[rt];
        a_lo = pa_lo[rt];
      } else {
        float4 xa = *(const float4*)(axf[rt] + k0);
        float4 xb = *(const float4*)(axf[rt] + k0 + 4);
#pragma unroll
        for (int jj = 0; jj < 4; ++jj) {
          ushort h, l;
          split2(((const float*)&xa)[jj], h, l);
          ((short*)&a_hi)[jj] = (short)h; ((short*)&a_lo)[jj] = (short)l;
          split2(((const float*)&xb)[jj], h, l);
          ((short*)&a_hi)[4 + jj] = (short)h; ((short*)&a_lo)[4 + jj] = (short)l;
        }
      }
#pragma unroll
      for (int ct = 0; ct < 4; ++ct) {
        acc[rt][ct] = MFMA16(a_hi, bh[ct], acc[rt][ct]);
        acc[rt][ct] = MFMA16(a_hi, bl[ct], acc[rt][ct]);
        acc[rt][ct] = MFMA16(a_lo, bh[ct], acc[rt][ct]);
      }
    }
    __syncthreads();                     // drains in-flight stage + syncs
    if constexpr (PRECVT) {
      if (c < 15) {
#pragma unroll
        for (int rt = 0; rt < 4; ++rt) { pa_hi[rt] = na_hi[rt]; pa_lo[rt] = na_lo[rt]; }
      }
    }
    buf ^= 1;
  }

  // ---- coalesced epilogue via wave-private LDS transpose (aliases sbuf) ----
  short* eph = sbuf + w * 2304;               // 16 rows x 72, hi plane
  short* epl = eph + 1152;                    // lo plane
  const int g0   = tn * 128 + wc * 64;        // wave-uniform 64-col block
  const int sect = (g0 % 192) >> 6;           // 0=q 1=k 2=v
  const int s    = g0 / 192;                  // n & 7
  float bv[4];
#pragma unroll
  for (int ct = 0; ct < 4; ++ct) bv[ct] = bqkv[g0 + ct * 16 + col16];

#pragma unroll
  for (int rt = 0; rt < 4; ++rt) {
#pragma unroll
    for (int ct = 0; ct < 4; ++ct) {
#pragma unroll
      for (int r = 0; r < 4; ++r) {
        const float val = acc[rt][ct][r] + bv[ct];
        const int o = (quad * 4 + r) * 72 + ct * 16 + col16;
        if (sect == 2) {
          eph[o] = (short)f2bf_rne(val);
        } else {
          ushort h, l; split2(val, h, l);
          eph[o] = (short)h; epl[o] = (short)l;
        }
      }
    }
#pragma unroll
    for (int p = 0; p < 2; ++p) {
      const int row = p * 8 + (lane >> 3);
      const int dsg = (lane & 7) * 8;
      const int grow = tmb * 128 + wr * 64 + rt * 16 + row;
      const int bhh = grow >> 8, a = grow & 255;
      const size_t idx = ((size_t)bhh * 2048 + 8 * a + s) * 64 + dsg;
      uint4 hv = *(const uint4*)(eph + row * 72 + dsg);
      if (sect == 0) {
        *(uint4*)(q_hi + idx) = hv;
        uint4 lv = *(const uint4*)(epl + row * 72 + dsg);
        *(uint4*)(q_lo + idx) = lv;
      } else if (sect == 1) {
        *(uint4*)(k_hi + idx) = hv;
        uint4 lv = *(const uint4*)(epl + row * 72 + dsg);
        *(uint4*)(k_lo + idx) = lv;
      } else {
        *(uint4*)(v_nat + idx) = hv;
      }
    }
  }
}

// ---------------------------------------------------------------------------
// K1b: v [bh][n][d] -> vT [bh][d][n].  Grid: 32 bh x 8 n-tiles(256) = 256.
// ---------------------------------------------------------------------------
__global__ __launch_bounds__(256) void vtrans_k(const ushort* __restrict__ v_nat,
                                                ushort* __restrict__ vT)
{
  const int t  = blockIdx.x & 7;
  const int bh = blockIdx.x >> 3;
  const int tid = threadIdx.x;
  const int nl = tid & 63;
  const int dg = tid >> 6;
  const size_t base = (size_t)bh * 2048 * 64;
#pragma unroll
  for (int p = 0; p < 2; ++p) {
    const int dseg = dg + p * 4;
#pragma unroll
    for (int nb = 0; nb < 4; ++nb) {
      const int n = t * 256 + nb * 64 + nl;
      uint4 vv = *(const uint4*)(v_nat + base + (size_t)n * 64 + dseg * 8);
      const ushort* pv = (const ushort*)&vv;
#pragma unroll
      for (int j = 0; j < 8; ++j)
        vT[base + (size_t)(dseg * 8 + j) * 2048 + n] = pv[j];
    }
  }
}

// ---------------------------------------------------------------------------
// K2: flash attention. R18 structure (swapped QK^T, packed softmax, scalar
// lsum) + R19: chunk loop unrolled x2 (buf compile-time -> immediate-folded
// addressing). Block = 512 thr (8 waves), wave = 16 q-rows, grid 512.
// ---------------------------------------------------------------------------
__global__ __launch_bounds__(512, 4) void attn_k(
    const ushort* __restrict__ q_hi, const ushort* __restrict__ q_lo,
    const ushort* __restrict__ k_hi, const ushort* __restrict__ k_lo,
    const ushort* __restrict__ vT, ushort* __restrict__ y)
{
  const int i  = blockIdx.x;
  const int bh = (i & 7) * 4 + (i >> 7);   // XCD-local bh group
  const int qt = (i >> 3) & 15;
  const int tid = threadIdx.x, lane = tid & 63, w = tid >> 6;  // w in [0,8)
  const int col16 = lane & 15, quad = lane >> 4;
  const int n7 = col16 & 7;

  // [buf][plane][4096]: kh, kl, vt planes of [64 rows][64 shorts], swizzled.
  // p at +24576: [wave8][16 q][64 k] granule-swizzled. 32768 shorts = 64KB.
  __shared__ short sbuf[32768];

  const size_t base = (size_t)bh * 2048 * 64;
  const int qw = qt * 128 + w * 16;        // wave-private 16 q-rows

  const ushort* khs = k_hi + base;
  const ushort* kls = k_lo + base;
  const ushort* vts = vT  + base;

  // per-lane staging geometry: lane covers LDS shorts [sub*512 + lane*8, +8)
  const int lrow = lane >> 3;               // row within 8-row group
  const int lx8  = ((lane & 7) ^ lrow) * 8; // inverse-swizzled 16B slot

  bf16x8 qh[2], ql[2];
#pragma unroll
  for (int ks = 0; ks < 2; ++ks) {
    const size_t off = base + (size_t)(qw + col16) * 64 + ks * 32 + quad * 8;
    qh[ks] = *(const bf16x8*)(q_hi + off);
    ql[ks] = *(const bf16x8*)(q_lo + off);
  }

  f32x4 oacc[4];
#pragma unroll
  for (int ct = 0; ct < 4; ++ct) oacc[ct] = (f32x4){0.f, 0.f, 0.f, 0.f};
  float lsum = 0.f;                        // scalar: q=col16 fixed per lane

  const float S2 = 11.541560327111707f;   // 8 * log2(e)

  short* wp0 = sbuf + 24576 + w * 1024;   // wave-private P: [16 q][64 k]

  // stage chunk cnext into buffer nb: 24 x 1KB blocks, 3 per wave
#define STAGE_CHUNK(cnext, nb)                                                \
  {                                                                           \
    _Pragma("unroll")                                                         \
    for (int ii = 0; ii < 3; ++ii) {                                          \
      const int ins = w * 3 + ii;                                             \
      const int plane = ins >> 3, sub = ins & 7;                              \
      short* dst = sbuf + ((nb) * 3 + plane) * 4096 + sub * 512;              \
      const ushort* src;                                                      \
      if (plane == 2)                                                         \
        src = vts + (size_t)(sub * 8 + lrow) * 2048 + (cnext) * 64 + lx8;     \
      else                                                                    \
        src = (plane ? kls : khs) + (cnext) * 4096 + sub * 512 + lrow * 64 + lx8; \
      gl_lds16(src, dst);                                                     \
    }                                                                         \
  }

  // one chunk body; BUF is a compile-time constant (0/1)
#define ATTN_CHUNK(C, BUF)                                                    \
  {                                                                           \
    if ((C) < 31) STAGE_CHUNK((C) + 1, (BUF) ^ 1);                            \
    const short* kb = sbuf + ((BUF) * 3) * 4096;                              \
    const short* lb = kb + 4096;                                              \
    const short* vb = kb + 8192;                                              \
    f32x4 sacc[4];                                                            \
    _Pragma("unroll")                                                         \
    for (int ct = 0; ct < 4; ++ct) sacc[ct] = (f32x4){0.f, 0.f, 0.f, 0.f};    \
    __builtin_amdgcn_s_setprio(1);                                            \
    _Pragma("unroll")                                                         \
    for (int ks = 0; ks < 2; ++ks) {                                          \
      _Pragma("unroll")                                                       \
      for (int ct = 0; ct < 4; ++ct) {                                        \
        const int off = (ct * 16 + col16) * 64 + (((ks * 4 + quad) ^ n7) << 3); \
        bf16x8 khf = *(const bf16x8*)(kb + off);                              \
        bf16x8 klf = *(const bf16x8*)(lb + off);                              \
        sacc[ct] = MFMA16(khf, qh[ks], sacc[ct]);                             \
        sacc[ct] = MFMA16(klf, qh[ks], sacc[ct]);                             \
        sacc[ct] = MFMA16(khf, ql[ks], sacc[ct]);                             \
      }                                                                       \
    }                                                                         \
    __builtin_amdgcn_s_setprio(0);                                            \
    _Pragma("unroll")                                                         \
    for (int ct = 0; ct < 4; ++ct) {                                          \
      union { float f; unsigned u; } p0, p1, p2, p3;                          \
      p0.f = __builtin_amdgcn_exp2f(fmaf(sacc[ct][0], S2, -128.0f));          \
      p1.f = __builtin_amdgcn_exp2f(fmaf(sacc[ct][1], S2, -128.0f));          \
      p2.f = __builtin_amdgcn_exp2f(fmaf(sacc[ct][2], S2, -128.0f));          \
      p3.f = __builtin_amdgcn_exp2f(fmaf(sacc[ct][3], S2, -128.0f));          \
      lsum += (p0.f + p1.f) + (p2.f + p3.f);                                  \
      const unsigned lo = (p0.u >> 16) | (p1.u & 0xffff0000u);                \
      const unsigned hi = (p2.u >> 16) | (p3.u & 0xffff0000u);                \
      const int g8 = (ct * 2 + (quad >> 1)) ^ n7;                             \
      uint2 pk; pk.x = lo; pk.y = hi;                                         \
      *(uint2*)(wp0 + col16 * 64 + (g8 << 3) + ((quad & 1) << 2)) = pk;       \
    }                                                                         \
    __builtin_amdgcn_s_setprio(1);                                            \
    _Pragma("unroll")                                                         \
    for (int ks = 0; ks < 2; ++ks) {                                          \
      bf16x8 ap = *(const bf16x8*)(wp0 + col16 * 64 +                         \
                                   (((ks * 4 + quad) ^ n7) << 3));            \
      _Pragma("unroll")                                                       \
      for (int ct = 0; ct < 4; ++ct) {                                        \
        const int voff = (ct * 16 + col16) * 64 + (((ks * 4 + quad) ^ n7) << 3); \
        bf16x8 vv = *(const bf16x8*)(vb + voff);                              \
        oacc[ct] = MFMA16(ap, vv, oacc[ct]);                                  \
      }                                                                       \
    }                                                                         \
    __builtin_amdgcn_s_setprio(0);                                            \
    __syncthreads();                                                          \
  }

  STAGE_CHUNK(0, 0);
  __syncthreads();

  for (int c = 0; c < 32; c += 2) {      // unrolled x2: BUF compile-time
    ATTN_CHUNK(c, 0);
    ATTN_CHUNK(c + 1, 1);
  }

  // epilogue: lsum covers quads' k-partials -> reduce over quads, then
  // fetch per-output-row inv via dynamic shuffle (row q lives at lane q).
  lsum += __shfl_xor(lsum, 16, 64);
  lsum += __shfl_xor(lsum, 32, 64);
#pragma unroll
  for (int r = 0; r < 4; ++r) {
    const float inv = 1.f / __shfl(lsum, quad * 4 + r, 64);
    const int n = qw + quad * 4 + r;
    const size_t orow = ((size_t)bh * 256 + (n >> 3)) * 512 + (n & 7) * 64;
#pragma unroll
    for (int ct = 0; ct < 4; ++ct)
      y[orow + ct * 16 + col16] = f2bf_rne(oacc[ct][r] * inv);
  }
#undef ATTN_CHUNK
#undef STAGE_CHUNK
}

// ---------------------------------------------------------------------------
// K3: out = y @ Wo + bo, 32x128 tiles (plain bf16 MFMA, f32 out). Grid 1024
// (4 blocks/CU), XCD-swizzled. Wave = 16 rows x 64 cols. Double-buffered B.
// ---------------------------------------------------------------------------
__global__ __launch_bounds__(256) void out_gemm_k(
    const ushort* __restrict__ y, const ushort* __restrict__ woT,
    const float* __restrict__ bo, float* __restrict__ out)
{
  const int i = blockIdx.x, j = i >> 3;
  const int tmb = (i & 7) * 32 + (j & 31);  // 256 row-strips of 32, XCD-grouped
  const int tn  = j >> 5;                   // [0,4) col-panel of 128
  const int tid = threadIdx.x, lane = tid & 63, w = tid >> 6;
  const int col16 = lane & 15, quad = lane >> 4;
  const int wr = w >> 1, wc = w & 1;

  __shared__ short b_lds[2][128][40];

  const int sn = tid >> 1, sk = (tid & 1) * 16;
  const ushort* bsrc = woT + (size_t)(tn * 128 + sn) * 512 + sk;

  const ushort* ay = y + (size_t)(tmb * 32 + wr * 16 + col16) * 512 + quad * 8;

  f32x4 acc[4];
#pragma unroll
  for (int ct = 0; ct < 4; ++ct) acc[ct] = (f32x4){0.f, 0.f, 0.f, 0.f};

  uint4 rb0 = *(const uint4*)(bsrc);
  uint4 rb1 = *(const uint4*)(bsrc + 8);
  *(uint4*)(&b_lds[0][sn][sk])     = rb0;
  *(uint4*)(&b_lds[0][sn][sk + 8]) = rb1;

  for (int c = 0; c < 16; ++c) {
    __syncthreads();
    if (c < 15) {
      const int k0 = (c + 1) * 32;
      rb0 = *(const uint4*)(bsrc + k0);
      rb1 = *(const uint4*)(bsrc + k0 + 8);
    }
    const int b = c & 1, k0 = c * 32;
    bf16x8 af = *(const bf16x8*)(ay + k0);
#pragma unroll
    for (int ct = 0; ct < 4; ++ct) {
      bf16x8 bfr = *(const bf16x8*)(&b_lds[b][wc * 64 + ct * 16 + col16][quad * 8]);
      acc[ct] = MFMA16(af, bfr, acc[ct]);
    }
    if (c < 15) {
      const int nb = b ^ 1;
      *(uint4*)(&b_lds[nb][sn][sk])     = rb0;
      *(uint4*)(&b_lds[nb][sn][sk + 8]) = rb1;
    }
  }
#pragma unroll
  for (int ct = 0; ct < 4; ++ct) {
    const int col = tn * 128 + wc * 64 + ct * 16 + col16;
    const float bval = bo[col];
#pragma unroll
    for (int r = 0; r < 4; ++r) {
      const int row = tmb * 32 + wr * 16 + quad * 4 + r;
      out[(size_t)row * 512 + col] = acc[ct][r] + bval;
    }
  }
}

// ---------------------------------------------------------------------------
extern "C" void kernel_launch(void* const* d_in, const int* in_sizes, int n_in,
                              void* d_out, int out_size, void* d_ws, size_t ws_size,
                              hipStream_t stream)
{
  const float* x    = (const float*)d_in[0];
  const float* Wqkv = (const float*)d_in[1];
  const float* bqkv = (const float*)d_in[2];
  const float* Wo   = (const float*)d_in[3];
  const float* bo   = (const float*)d_in[4];
  float* out = (float*)d_out;

  // ws (ushort elems). Base (R6-proven, 54.0 MB): weights + q/k/v planes.
  ushort* wT_hi = (ushort*)d_ws;                    //  786432 (chunked layout)
  ushort* wT_lo = wT_hi + 786432;                   //  786432
  ushort* woT   = wT_lo + 786432;                   //  262144
  ushort* q_hi  = woT   + 262144;                   // 4194304 each below
  ushort* q_lo  = q_hi  + 4194304;
  ushort* k_hi  = q_lo  + 4194304;
  ushort* k_lo  = k_hi  + 4194304;
  ushort* v_nat = k_lo  + 4194304;
  ushort* tail  = v_nat + 4194304;

  // Roomy path (62.4 MB): xh/xl planes; vT aliases xh, y aliases xl (both
  // dead after K1). ws_size is launch-invariant -> stable graph capture.
  const bool roomy = ws_size >= 62390272ULL;
  ushort *xh, *xl, *vT, *y;
  if (roomy) {
    xh = tail; xl = tail + 4194304;
    vT = xh;   y  = xl;                 // reused post-K1
  } else {
    xh = xl = nullptr;
    vT = tail; y = v_nat;               // R6 mapping (54.0 MB, proven)
  }

  if (roomy) {
    cvt_k<true><<<8192, 256, 0, stream>>>(Wqkv, Wo, x, wT_hi, wT_lo, woT, xh, xl);
    qkv_gemm_k<true><<<768, 256, 0, stream>>>(x, xh, xl, wT_hi, wT_lo, bqkv,
                                              q_hi, q_lo, k_hi, k_lo, v_nat);
  } else {
    cvt_k<false><<<4096, 256, 0, stream>>>(Wqkv, Wo, x, wT_hi, wT_lo, woT,
                                           nullptr, nullptr);
    qkv_gemm_k<false><<<768, 256, 0, stream>>>(x, nullptr, nullptr, wT_hi, wT_lo,
                                               bqkv, q_hi, q_lo, k_hi, k_lo, v_nat);
  }
  vtrans_k<<<256, 256, 0, stream>>>(v_nat, vT);
  attn_k<<<512, 512, 0, stream>>>(q_hi, q_lo, k_hi, k_lo, vT, y);
  out_gemm_k<<<1024, 256, 0, stream>>>(y, woT, bo, out);
}

// Round 9
// 223.690 us; speedup vs baseline: 1.0399x; 1.0399x over previous
//
#include <hip/hip_runtime.h>
#include <hip/hip_bf16.h>
#include <math.h>

// ---------------------------------------------------------------------------
// MultiHeadSelfAttention  B=4 N=2048 E=512 H=8 DK=DV=64   (f32 in / f32 out)
// Split-bf16 (hi/lo) MFMA on the attention-critical path.
//
// Reference quirks (verified passing):
//  * qkv.reshape(B,H,N,192) is token-mixing: with GEMM col g:
//    s=g/192, sect=(g%192)/64, d=g%64, n=8a+s (a=row%256, bh=row/256).
//  * y.reshape: y[b,h,n,d] -> yws[bh*256 + (n>>3)][(n&7)*64 + d]
//  * qk / DK**-0.5 == qk * 8.0
//
// R19 post-mortem (clean attribution, two independent kernels changed):
//  * attn unroll x2 WORKED: 74.3 -> 71.8us (MfmaUtil 41.8, VALU 45.7).
//    MFMA busy 30us ~= 33us matrix-pipe floor; VALU 33us; pipes serialized
//    by barrier phase-lock -> attn is near its structural floor (~66us).
//  * qkv A-prefetch REGRESSED ~10us (total 225.2 -> 232.6): +64 VGPR for
//    prefetch arrays crossed a pressure/scheduling cliff (R10's lesson).
//
// R20 (this round): REVERT qkv_gemm to the R14/R18 proven version (no
// A-prefetch). attn keeps R19 unroll. cvt/vtrans/out_gemm byte-identical.
// ---------------------------------------------------------------------------

typedef __attribute__((ext_vector_type(8))) short bf16x8;
typedef __attribute__((ext_vector_type(4))) float f32x4;

#define MFMA16(a, b, c) __builtin_amdgcn_mfma_f32_16x16x32_bf16((a), (b), (c), 0, 0, 0)

__device__ __forceinline__ ushort f2bf_rne(float f) {
  union { float f; unsigned u; } v; v.f = f;
  return (ushort)((v.u + 0x7fffu + ((v.u >> 16) & 1u)) >> 16);
}
__device__ __forceinline__ float bf2f(ushort h) {
  union { float f; unsigned u; } v; v.u = ((unsigned)h) << 16; return v.f;
}
__device__ __forceinline__ void split2(float f, ushort& hi, ushort& lo) {
  union { float f; unsigned u; } v; v.f = f;
  hi = (ushort)(v.u >> 16);
  union { float f; unsigned u; } r; r.f = f - bf2f(hi);
  lo = (ushort)(r.u >> 16);          // trunc lo: rel err ~2^-16.5, negligible
}

// async global->LDS, 16B per lane; lds ptr must be wave-uniform (HW adds lane*16)
typedef __attribute__((address_space(3))) unsigned int lds_uint;
typedef const __attribute__((address_space(1))) unsigned int glob_uint;
__device__ __forceinline__ void gl_lds16(const ushort* g, short* l) {
  __builtin_amdgcn_global_load_lds((glob_uint*)g, (lds_uint*)l, 16, 0, 0);
}

// ---------------------------------------------------------------------------
// K0 (fused): W_qkv -> wT_hi/lo K-CHUNKED [c16][n1536][ks32] (contiguous 8KB
// per (tn,c) stage tile); W_o -> woT; and if ROOMY, x -> xh/xl bf16 planes.
// ---------------------------------------------------------------------------
template <bool ROOMY>
__global__ __launch_bounds__(256) void cvt_k(const float* __restrict__ wqkv,
                                             const float* __restrict__ wo,
                                             const float* __restrict__ x,
                                             ushort* __restrict__ wT_hi,
                                             ushort* __restrict__ wT_lo,
                                             ushort* __restrict__ woT,
                                             ushort* __restrict__ xh,
                                             ushort* __restrict__ xl)
{
  const int gid = blockIdx.x * 256 + threadIdx.x;
  if (gid < 786432) {
    const int c   = gid / 49152;          // k-chunk 0..15
    const int rem = gid - c * 49152;
    const int n   = rem >> 5;             // 0..1535
    const int k   = c * 32 + (rem & 31);  // 0..511
    ushort hi, lo; split2(wqkv[(size_t)k * 1536 + n], hi, lo);
    wT_hi[gid] = hi; wT_lo[gid] = lo;     // write-contiguous in chunked layout
  } else if (gid < 1048576) {
    const int g = gid - 786432;
    const int n = g >> 9, k = g & 511;
    woT[g] = f2bf_rne(wo[(size_t)k * 512 + n]);
  } else if (ROOMY) {
    const int g = gid - 1048576;        // 1048576 vec4 slots
    float4 v = ((const float4*)x)[g];
    ushort4 hh, ll;
    split2(v.x, hh.x, ll.x); split2(v.y, hh.y, ll.y);
    split2(v.z, hh.z, ll.z); split2(v.w, hh.w, ll.w);
    ((ushort4*)xh)[g] = hh;
    ((ushort4*)xl)[g] = ll;
  }
}

// ---------------------------------------------------------------------------
// K1: qkv GEMM, 128x128 tile/block (4 waves 2x2, wave = 64x64 = 4x4 acc).
// B staged via global_load_lds(16B) from chunked wT (R14, proven). R20:
// reverted to R18 state (no A-prefetch; R19's +64 VGPR regressed ~10us).
// ---------------------------------------------------------------------------
template <bool PRECVT>
__global__ __launch_bounds__(256) void qkv_gemm_k(
    const float* __restrict__ x,
    const ushort* __restrict__ xh, const ushort* __restrict__ xl,
    const ushort* __restrict__ wT_hi, const ushort* __restrict__ wT_lo,
    const float* __restrict__ bqkv,
    ushort* __restrict__ q_hi, ushort* __restrict__ q_lo,
    ushort* __restrict__ k_hi, ushort* __restrict__ k_lo,
    ushort* __restrict__ v_nat)
{
  const int i = blockIdx.x, j = i >> 3;
  const int tmb = (i & 7) * 8 + (j & 7);   // row-strip, XCD-grouped
  const int tn  = j >> 3;                  // col-panel [0,12)
  const int tid = threadIdx.x, lane = tid & 63, w = tid >> 6;
  const int col16 = lane & 15, quad = lane >> 4;
  const int wr = w >> 1, wc = w & 1;

  __shared__ short sbuf[16384];   // 32KB: hi@[buf*4096], lo@[8192+buf*4096]

  // per-thread global src offset within a chunk (bytes: w*2048 + lane*16)
  const int wl   = w * 1024 + lane * 8;    // ushorts
  const int ldsw = w * 1024;               // wave-uniform LDS offset (ushorts)
  const ushort* shp = wT_hi + (size_t)tn * 4096 + wl;
  const ushort* slp = wT_lo + (size_t)tn * 4096 + wl;

  const float*  axf[4];
  const ushort *axh[4], *axl[4];
#pragma unroll
  for (int rt = 0; rt < 4; ++rt) {
    const size_t rowoff = (size_t)(tmb * 128 + wr * 64 + rt * 16 + col16) * 512 + quad * 8;
    axf[rt] = x  + rowoff;
    axh[rt] = xh + rowoff;
    axl[rt] = xl + rowoff;
  }

  f32x4 acc[4][4];
#pragma unroll
  for (int rt = 0; rt < 4; ++rt)
#pragma unroll
    for (int ct = 0; ct < 4; ++ct) acc[rt][ct] = (f32x4){0.f, 0.f, 0.f, 0.f};

  // prologue: stage chunk 0 into buf 0
  gl_lds16(shp,       sbuf + ldsw);
  gl_lds16(shp + 512, sbuf + ldsw + 512);
  gl_lds16(slp,       sbuf + 8192 + ldsw);
  gl_lds16(slp + 512, sbuf + 8192 + ldsw + 512);
  __syncthreads();

  int buf = 0;
#pragma unroll
  for (int c = 0; c < 16; ++c) {
    if (c < 15) {                        // issue next-chunk stages (async)
      const size_t co = (size_t)(c + 1) * 49152;
      const int nb = (buf ^ 1) * 4096;
      gl_lds16(shp + co,       sbuf + nb + ldsw);
      gl_lds16(shp + co + 512, sbuf + nb + ldsw + 512);
      gl_lds16(slp + co,       sbuf + 8192 + nb + ldsw);
      gl_lds16(slp + co + 512, sbuf + 8192 + nb + ldsw + 512);
    }
    const int k0 = c * 32;
    const short* bhb = sbuf + buf * 4096;
    const short* blb = sbuf + 8192 + buf * 4096;

    bf16x8 bh[4], bl[4];
#pragma unroll
    for (int ct = 0; ct < 4; ++ct) {
      const int roff = (wc * 64 + ct * 16 + col16) * 32 + quad * 8;
      bh[ct] = *(const bf16x8*)(bhb + roff);
      bl[ct] = *(const bf16x8*)(blb + roff);
    }
#pragma unroll
    for (int rt = 0; rt < 4; ++rt) {
      bf16x8 a_hi, a_lo;
      if constexpr (PRECVT) {
        a_hi = *(const bf16x8*)(axh[rt] + k0);
        a_lo = *(const bf16x8*)(axl[rt] + k0);
      } else {
        float4 xa = *(const float4*)(axf[rt] + k0);
        float4 xb = *(const float4*)(axf[rt] + k0 + 4);
#pragma unroll
        for (int jj = 0; jj < 4; ++jj) {
          ushort h, l;
          split2(((const float*)&xa)[jj], h, l);
          ((short*)&a_hi)[jj] = (short)h; ((short*)&a_lo)[jj] = (short)l;
          split2(((const float*)&xb)[jj], h, l);
          ((short*)&a_hi)[4 + jj] = (short)h; ((short*)&a_lo)[4 + jj] = (short)l;
        }
      }
#pragma unroll
      for (int ct = 0; ct < 4; ++ct) {
        acc[rt][ct] = MFMA16(a_hi, bh[ct], acc[rt][ct]);
        acc[rt][ct] = MFMA16(a_hi, bl[ct], acc[rt][ct]);
        acc[rt][ct] = MFMA16(a_lo, bh[ct], acc[rt][ct]);
      }
    }
    __syncthreads();                     // drains in-flight stage + syncs
    buf ^= 1;
  }

  // ---- coalesced epilogue via wave-private LDS transpose (aliases sbuf) ----
  short* eph = sbuf + w * 2304;               // 16 rows x 72, hi plane
  short* epl = eph + 1152;                    // lo plane
  const int g0   = tn * 128 + wc * 64;        // wave-uniform 64-col block
  const int sect = (g0 % 192) >> 6;           // 0=q 1=k 2=v
  const int s    = g0 / 192;                  // n & 7
  float bv[4];
#pragma unroll
  for (int ct = 0; ct < 4; ++ct) bv[ct] = bqkv[g0 + ct * 16 + col16];

#pragma unroll
  for (int rt = 0; rt < 4; ++rt) {
#pragma unroll
    for (int ct = 0; ct < 4; ++ct) {
#pragma unroll
      for (int r = 0; r < 4; ++r) {
        const float val = acc[rt][ct][r] + bv[ct];
        const int o = (quad * 4 + r) * 72 + ct * 16 + col16;
        if (sect == 2) {
          eph[o] = (short)f2bf_rne(val);
        } else {
          ushort h, l; split2(val, h, l);
          eph[o] = (short)h; epl[o] = (short)l;
        }
      }
    }
#pragma unroll
    for (int p = 0; p < 2; ++p) {
      const int row = p * 8 + (lane >> 3);
      const int dsg = (lane & 7) * 8;
      const int grow = tmb * 128 + wr * 64 + rt * 16 + row;
      const int bhh = grow >> 8, a = grow & 255;
      const size_t idx = ((size_t)bhh * 2048 + 8 * a + s) * 64 + dsg;
      uint4 hv = *(const uint4*)(eph + row * 72 + dsg);
      if (sect == 0) {
        *(uint4*)(q_hi + idx) = hv;
        uint4 lv = *(const uint4*)(epl + row * 72 + dsg);
        *(uint4*)(q_lo + idx) = lv;
      } else if (sect == 1) {
        *(uint4*)(k_hi + idx) = hv;
        uint4 lv = *(const uint4*)(epl + row * 72 + dsg);
        *(uint4*)(k_lo + idx) = lv;
      } else {
        *(uint4*)(v_nat + idx) = hv;
      }
    }
  }
}

// ---------------------------------------------------------------------------
// K1b: v [bh][n][d] -> vT [bh][d][n].  Grid: 32 bh x 8 n-tiles(256) = 256.
// ---------------------------------------------------------------------------
__global__ __launch_bounds__(256) void vtrans_k(const ushort* __restrict__ v_nat,
                                                ushort* __restrict__ vT)
{
  const int t  = blockIdx.x & 7;
  const int bh = blockIdx.x >> 3;
  const int tid = threadIdx.x;
  const int nl = tid & 63;
  const int dg = tid >> 6;
  const size_t base = (size_t)bh * 2048 * 64;
#pragma unroll
  for (int p = 0; p < 2; ++p) {
    const int dseg = dg + p * 4;
#pragma unroll
    for (int nb = 0; nb < 4; ++nb) {
      const int n = t * 256 + nb * 64 + nl;
      uint4 vv = *(const uint4*)(v_nat + base + (size_t)n * 64 + dseg * 8);
      const ushort* pv = (const ushort*)&vv;
#pragma unroll
      for (int j = 0; j < 8; ++j)
        vT[base + (size_t)(dseg * 8 + j) * 2048 + n] = pv[j];
    }
  }
}

// ---------------------------------------------------------------------------
// K2: flash attention. R18 structure (swapped QK^T, packed softmax, scalar
// lsum) + R19 unroll x2 (buf compile-time). Block = 512 thr (8 waves),
// wave = 16 q-rows, grid 512. Proven 71.8us.
// ---------------------------------------------------------------------------
__global__ __launch_bounds__(512, 4) void attn_k(
    const ushort* __restrict__ q_hi, const ushort* __restrict__ q_lo,
    const ushort* __restrict__ k_hi, const ushort* __restrict__ k_lo,
    const ushort* __restrict__ vT, ushort* __restrict__ y)
{
  const int i  = blockIdx.x;
  const int bh = (i & 7) * 4 + (i >> 7);   // XCD-local bh group
  const int qt = (i >> 3) & 15;
  const int tid = threadIdx.x, lane = tid & 63, w = tid >> 6;  // w in [0,8)
  const int col16 = lane & 15, quad = lane >> 4;
  const int n7 = col16 & 7;

  // [buf][plane][4096]: kh, kl, vt planes of [64 rows][64 shorts], swizzled.
  // p at +24576: [wave8][16 q][64 k] granule-swizzled. 32768 shorts = 64KB.
  __shared__ short sbuf[32768];

  const size_t base = (size_t)bh * 2048 * 64;
  const int qw = qt * 128 + w * 16;        // wave-private 16 q-rows

  const ushort* khs = k_hi + base;
  const ushort* kls = k_lo + base;
  const ushort* vts = vT  + base;

  // per-lane staging geometry: lane covers LDS shorts [sub*512 + lane*8, +8)
  const int lrow = lane >> 3;               // row within 8-row group
  const int lx8  = ((lane & 7) ^ lrow) * 8; // inverse-swizzled 16B slot

  bf16x8 qh[2], ql[2];
#pragma unroll
  for (int ks = 0; ks < 2; ++ks) {
    const size_t off = base + (size_t)(qw + col16) * 64 + ks * 32 + quad * 8;
    qh[ks] = *(const bf16x8*)(q_hi + off);
    ql[ks] = *(const bf16x8*)(q_lo + off);
  }

  f32x4 oacc[4];
#pragma unroll
  for (int ct = 0; ct < 4; ++ct) oacc[ct] = (f32x4){0.f, 0.f, 0.f, 0.f};
  float lsum = 0.f;                        // scalar: q=col16 fixed per lane

  const float S2 = 11.541560327111707f;   // 8 * log2(e)

  short* wp0 = sbuf + 24576 + w * 1024;   // wave-private P: [16 q][64 k]

  // stage chunk cnext into buffer nb: 24 x 1KB blocks, 3 per wave
#define STAGE_CHUNK(cnext, nb)                                                \
  {                                                                           \
    _Pragma("unroll")                                                         \
    for (int ii = 0; ii < 3; ++ii) {                                          \
      const int ins = w * 3 + ii;                                             \
      const int plane = ins >> 3, sub = ins & 7;                              \
      short* dst = sbuf + ((nb) * 3 + plane) * 4096 + sub * 512;              \
      const ushort* src;                                                      \
      if (plane == 2)                                                         \
        src = vts + (size_t)(sub * 8 + lrow) * 2048 + (cnext) * 64 + lx8;     \
      else                                                                    \
        src = (plane ? kls : khs) + (cnext) * 4096 + sub * 512 + lrow * 64 + lx8; \
      gl_lds16(src, dst);                                                     \
    }                                                                         \
  }

  // one chunk body; BUF is a compile-time constant (0/1)
#define ATTN_CHUNK(C, BUF)                                                    \
  {                                                                           \
    if ((C) < 31) STAGE_CHUNK((C) + 1, (BUF) ^ 1);                            \
    const short* kb = sbuf + ((BUF) * 3) * 4096;                              \
    const short* lb = kb + 4096;                                              \
    const short* vb = kb + 8192;                                              \
    f32x4 sacc[4];                                                            \
    _Pragma("unroll")                                                         \
    for (int ct = 0; ct < 4; ++ct) sacc[ct] = (f32x4){0.f, 0.f, 0.f, 0.f};    \
    __builtin_amdgcn_s_setprio(1);                                            \
    _Pragma("unroll")                                                         \
    for (int ks = 0; ks < 2; ++ks) {                                          \
      _Pragma("unroll")                                                       \
      for (int ct = 0; ct < 4; ++ct) {                                        \
        const int off = (ct * 16 + col16) * 64 + (((ks * 4 + quad) ^ n7) << 3); \
        bf16x8 khf = *(const bf16x8*)(kb + off);                              \
        bf16x8 klf = *(const bf16x8*)(lb + off);                              \
        sacc[ct] = MFMA16(khf, qh[ks], sacc[ct]);                             \
        sacc[ct] = MFMA16(klf, qh[ks], sacc[ct]);                             \
        sacc[ct] = MFMA16(khf, ql[ks], sacc[ct]);                             \
      }                                                                       \
    }                                                                         \
    __builtin_amdgcn_s_setprio(0);                                            \
    _Pragma("unroll")                                                         \
    for (int ct = 0; ct < 4; ++ct) {                                          \
      union { float f; unsigned u; } p0, p1, p2, p3;                          \
      p0.f = __builtin_amdgcn_exp2f(fmaf(sacc[ct][0], S2, -128.0f));          \
      p1.f = __builtin_amdgcn_exp2f(fmaf(sacc[ct][1], S2, -128.0f));          \
      p2.f = __builtin_amdgcn_exp2f(fmaf(sacc[ct][2], S2, -128.0f));          \
      p3.f = __builtin_amdgcn_exp2f(fmaf(sacc[ct][3], S2, -128.0f));          \
      lsum += (p0.f + p1.f) + (p2.f + p3.f);                                  \
      const unsigned lo = (p0.u >> 16) | (p1.u & 0xffff0000u);                \
      const unsigned hi = (p2.u >> 16) | (p3.u & 0xffff0000u);                \
      const int g8 = (ct * 2 + (quad >> 1)) ^ n7;                             \
      uint2 pk; pk.x = lo; pk.y = hi;                                         \
      *(uint2*)(wp0 + col16 * 64 + (g8 << 3) + ((quad & 1) << 2)) = pk;       \
    }                                                                         \
    __builtin_amdgcn_s_setprio(1);                                            \
    _Pragma("unroll")                                                         \
    for (int ks = 0; ks < 2; ++ks) {                                          \
      bf16x8 ap = *(const bf16x8*)(wp0 + col16 * 64 +                         \
                                   (((ks * 4 + quad) ^ n7) << 3));            \
      _Pragma("unroll")                                                       \
      for (int ct = 0; ct < 4; ++ct) {                                        \
        const int voff = (ct * 16 + col16) * 64 + (((ks * 4 + quad) ^ n7) << 3); \
        bf16x8 vv = *(const bf16x8*)(vb + voff);                              \
        oacc[ct] = MFMA16(ap, vv, oacc[ct]);                                  \
      }                                                                       \
    }                                                                         \
    __builtin_amdgcn_s_setprio(0);                                            \
    __syncthreads();                                                          \
  }

  STAGE_CHUNK(0, 0);
  __syncthreads();

  for (int c = 0; c < 32; c += 2) {      // unrolled x2: BUF compile-time
    ATTN_CHUNK(c, 0);
    ATTN_CHUNK(c + 1, 1);
  }

  // epilogue: lsum covers quads' k-partials -> reduce over quads, then
  // fetch per-output-row inv via dynamic shuffle (row q lives at lane q).
  lsum += __shfl_xor(lsum, 16, 64);
  lsum += __shfl_xor(lsum, 32, 64);
#pragma unroll
  for (int r = 0; r < 4; ++r) {
    const float inv = 1.f / __shfl(lsum, quad * 4 + r, 64);
    const int n = qw + quad * 4 + r;
    const size_t orow = ((size_t)bh * 256 + (n >> 3)) * 512 + (n & 7) * 64;
#pragma unroll
    for (int ct = 0; ct < 4; ++ct)
      y[orow + ct * 16 + col16] = f2bf_rne(oacc[ct][r] * inv);
  }
#undef ATTN_CHUNK
#undef STAGE_CHUNK
}

// ---------------------------------------------------------------------------
// K3: out = y @ Wo + bo, 32x128 tiles (plain bf16 MFMA, f32 out). Grid 1024
// (4 blocks/CU), XCD-swizzled. Wave = 16 rows x 64 cols. Double-buffered B.
// ---------------------------------------------------------------------------
__global__ __launch_bounds__(256) void out_gemm_k(
    const ushort* __restrict__ y, const ushort* __restrict__ woT,
    const float* __restrict__ bo, float* __restrict__ out)
{
  const int i = blockIdx.x, j = i >> 3;
  const int tmb = (i & 7) * 32 + (j & 31);  // 256 row-strips of 32, XCD-grouped
  const int tn  = j >> 5;                   // [0,4) col-panel of 128
  const int tid = threadIdx.x, lane = tid & 63, w = tid >> 6;
  const int col16 = lane & 15, quad = lane >> 4;
  const int wr = w >> 1, wc = w & 1;

  __shared__ short b_lds[2][128][40];

  const int sn = tid >> 1, sk = (tid & 1) * 16;
  const ushort* bsrc = woT + (size_t)(tn * 128 + sn) * 512 + sk;

  const ushort* ay = y + (size_t)(tmb * 32 + wr * 16 + col16) * 512 + quad * 8;

  f32x4 acc[4];
#pragma unroll
  for (int ct = 0; ct < 4; ++ct) acc[ct] = (f32x4){0.f, 0.f, 0.f, 0.f};

  uint4 rb0 = *(const uint4*)(bsrc);
  uint4 rb1 = *(const uint4*)(bsrc + 8);
  *(uint4*)(&b_lds[0][sn][sk])     = rb0;
  *(uint4*)(&b_lds[0][sn][sk + 8]) = rb1;

  for (int c = 0; c < 16; ++c) {
    __syncthreads();
    if (c < 15) {
      const int k0 = (c + 1) * 32;
      rb0 = *(const uint4*)(bsrc + k0);
      rb1 = *(const uint4*)(bsrc + k0 + 8);
    }
    const int b = c & 1, k0 = c * 32;
    bf16x8 af = *(const bf16x8*)(ay + k0);
#pragma unroll
    for (int ct = 0; ct < 4; ++ct) {
      bf16x8 bfr = *(const bf16x8*)(&b_lds[b][wc * 64 + ct * 16 + col16][quad * 8]);
      acc[ct] = MFMA16(af, bfr, acc[ct]);
    }
    if (c < 15) {
      const int nb = b ^ 1;
      *(uint4*)(&b_lds[nb][sn][sk])     = rb0;
      *(uint4*)(&b_lds[nb][sn][sk + 8]) = rb1;
    }
  }
#pragma unroll
  for (int ct = 0; ct < 4; ++ct) {
    const int col = tn * 128 + wc * 64 + ct * 16 + col16;
    const float bval = bo[col];
#pragma unroll
    for (int r = 0; r < 4; ++r) {
      const int row = tmb * 32 + wr * 16 + quad * 4 + r;
      out[(size_t)row * 512 + col] = acc[ct][r] + bval;
    }
  }
}

// ---------------------------------------------------------------------------
extern "C" void kernel_launch(void* const* d_in, const int* in_sizes, int n_in,
                              void* d_out, int out_size, void* d_ws, size_t ws_size,
                              hipStream_t stream)
{
  const float* x    = (const float*)d_in[0];
  const float* Wqkv = (const float*)d_in[1];
  const float* bqkv = (const float*)d_in[2];
  const float* Wo   = (const float*)d_in[3];
  const float* bo   = (const float*)d_in[4];
  float* out = (float*)d_out;

  // ws (ushort elems). Base (R6-proven, 54.0 MB): weights + q/k/v planes.
  ushort* wT_hi = (ushort*)d_ws;                    //  786432 (chunked layout)
  ushort* wT_lo = wT_hi + 786432;                   //  786432
  ushort* woT   = wT_lo + 786432;                   //  262144
  ushort* q_hi  = woT   + 262144;                   // 4194304 each below
  ushort* q_lo  = q_hi  + 4194304;
  ushort* k_hi  = q_lo  + 4194304;
  ushort* k_lo  = k_hi  + 4194304;
  ushort* v_nat = k_lo  + 4194304;
  ushort* tail  = v_nat + 4194304;

  // Roomy path (62.4 MB): xh/xl planes; vT aliases xh, y aliases xl (both
  // dead after K1). ws_size is launch-invariant -> stable graph capture.
  const bool roomy = ws_size >= 62390272ULL;
  ushort *xh, *xl, *vT, *y;
  if (roomy) {
    xh = tail; xl = tail + 4194304;
    vT = xh;   y  = xl;                 // reused post-K1
  } else {
    xh = xl = nullptr;
    vT = tail; y = v_nat;               // R6 mapping (54.0 MB, proven)
  }

  if (roomy) {
    cvt_k<true><<<8192, 256, 0, stream>>>(Wqkv, Wo, x, wT_hi, wT_lo, woT, xh, xl);
    qkv_gemm_k<true><<<768, 256, 0, stream>>>(x, xh, xl, wT_hi, wT_lo, bqkv,
                                              q_hi, q_lo, k_hi, k_lo, v_nat);
  } else {
    cvt_k<false><<<4096, 256, 0, stream>>>(Wqkv, Wo, x, wT_hi, wT_lo, woT,
                                           nullptr, nullptr);
    qkv_gemm_k<false><<<768, 256, 0, stream>>>(x, nullptr, nullptr, wT_hi, wT_lo,
                                               bqkv, q_hi, q_lo, k_hi, k_lo, v_nat);
  }
  vtrans_k<<<256, 256, 0, stream>>>(v_nat, vT);
  attn_k<<<512, 512, 0, stream>>>(q_hi, q_lo, k_hi, k_lo, vT, y);
  out_gemm_k<<<1024, 256, 0, stream>>>(y, woT, bo, out);
}

// Round 10
// 222.592 us; speedup vs baseline: 1.0450x; 1.0049x over previous
//
#include <hip/hip_runtime.h>
#include <hip/hip_bf16.h>
#include <math.h>

// ---------------------------------------------------------------------------
// MultiHeadSelfAttention  B=4 N=2048 E=512 H=8 DK=DV=64   (f32 in / f32 out)
// Split-bf16 (hi/lo) MFMA on the attention-critical path.
//
// Reference quirks (verified passing):
//  * qkv.reshape(B,H,N,192) is token-mixing: with GEMM col g:
//    s=g/192, sect=(g%192)/64, d=g%64, n=8a+s (a=row%256, bh=row/256).
//  * y.reshape: y[b,h,n,d] -> yws[bh*256 + (n>>3)][(n&7)*64 + d]
//  * qk / DK**-0.5 == qk * 8.0
//
// R20 post-mortem: revert landed as predicted (232.6 -> 223.7, best).
// attn 72.5us = its VALU/MFMA-serialized floor. Non-attn ~151us hidden:
// qkv ~66 (MFMA util ~23%, A-direct latency; full A+B staging blocked by
// 64KB-LDS occupancy cliff + grid-768 tail), out_gemm ~20-25 (last
// reg-staged GEMM), vtrans ~8-10 (coalesced both ways, near floor).
//
// R21 (this round): out_gemm converted to the R14-proven gl_lds B-staging:
//  * cvt writes woT K-CHUNKED [c16][n512][ks32] (same scheme as wT).
//  * out_gemm: B staged via 2x gl_lds16/thread/chunk, linear LDS 16KB dbuf
//    (was 20KB reg-staged [40]-stride), barrier at loop bottom (R14
//    template). MFMA order identical -> bit-identical output.
//  * attn/qkv/vtrans byte-identical (single-change discipline).
// ---------------------------------------------------------------------------

typedef __attribute__((ext_vector_type(8))) short bf16x8;
typedef __attribute__((ext_vector_type(4))) float f32x4;

#define MFMA16(a, b, c) __builtin_amdgcn_mfma_f32_16x16x32_bf16((a), (b), (c), 0, 0, 0)

__device__ __forceinline__ ushort f2bf_rne(float f) {
  union { float f; unsigned u; } v; v.f = f;
  return (ushort)((v.u + 0x7fffu + ((v.u >> 16) & 1u)) >> 16);
}
__device__ __forceinline__ float bf2f(ushort h) {
  union { float f; unsigned u; } v; v.u = ((unsigned)h) << 16; return v.f;
}
__device__ __forceinline__ void split2(float f, ushort& hi, ushort& lo) {
  union { float f; unsigned u; } v; v.f = f;
  hi = (ushort)(v.u >> 16);
  union { float f; unsigned u; } r; r.f = f - bf2f(hi);
  lo = (ushort)(r.u >> 16);          // trunc lo: rel err ~2^-16.5, negligible
}

// async global->LDS, 16B per lane; lds ptr must be wave-uniform (HW adds lane*16)
typedef __attribute__((address_space(3))) unsigned int lds_uint;
typedef const __attribute__((address_space(1))) unsigned int glob_uint;
__device__ __forceinline__ void gl_lds16(const ushort* g, short* l) {
  __builtin_amdgcn_global_load_lds((glob_uint*)g, (lds_uint*)l, 16, 0, 0);
}

// ---------------------------------------------------------------------------
// K0 (fused): W_qkv -> wT_hi/lo K-CHUNKED [c16][n1536][ks32]; W_o -> woT
// K-CHUNKED [c16][n512][ks32] (R21); and if ROOMY, x -> xh/xl bf16 planes.
// ---------------------------------------------------------------------------
template <bool ROOMY>
__global__ __launch_bounds__(256) void cvt_k(const float* __restrict__ wqkv,
                                             const float* __restrict__ wo,
                                             const float* __restrict__ x,
                                             ushort* __restrict__ wT_hi,
                                             ushort* __restrict__ wT_lo,
                                             ushort* __restrict__ woT,
                                             ushort* __restrict__ xh,
                                             ushort* __restrict__ xl)
{
  const int gid = blockIdx.x * 256 + threadIdx.x;
  if (gid < 786432) {
    const int c   = gid / 49152;          // k-chunk 0..15
    const int rem = gid - c * 49152;
    const int n   = rem >> 5;             // 0..1535
    const int k   = c * 32 + (rem & 31);  // 0..511
    ushort hi, lo; split2(wqkv[(size_t)k * 1536 + n], hi, lo);
    wT_hi[gid] = hi; wT_lo[gid] = lo;     // write-contiguous in chunked layout
  } else if (gid < 1048576) {
    const int g   = gid - 786432;         // 262144 elements
    const int c   = g / 16384;            // k-chunk 0..15
    const int rem = g - c * 16384;
    const int n   = rem >> 5;             // 0..511
    const int k   = c * 32 + (rem & 31);  // 0..511
    woT[g] = f2bf_rne(wo[(size_t)k * 512 + n]);   // chunked [c][n][ks]
  } else if (ROOMY) {
    const int g = gid - 1048576;        // 1048576 vec4 slots
    float4 v = ((const float4*)x)[g];
    ushort4 hh, ll;
    split2(v.x, hh.x, ll.x); split2(v.y, hh.y, ll.y);
    split2(v.z, hh.z, ll.z); split2(v.w, hh.w, ll.w);
    ((ushort4*)xh)[g] = hh;
    ((ushort4*)xl)[g] = ll;
  }
}

// ---------------------------------------------------------------------------
// K1: qkv GEMM, 128x128 tile/block (4 waves 2x2, wave = 64x64 = 4x4 acc).
// B staged via global_load_lds(16B) from chunked wT (R14, proven).
// ---------------------------------------------------------------------------
template <bool PRECVT>
__global__ __launch_bounds__(256) void qkv_gemm_k(
    const float* __restrict__ x,
    const ushort* __restrict__ xh, const ushort* __restrict__ xl,
    const ushort* __restrict__ wT_hi, const ushort* __restrict__ wT_lo,
    const float* __restrict__ bqkv,
    ushort* __restrict__ q_hi, ushort* __restrict__ q_lo,
    ushort* __restrict__ k_hi, ushort* __restrict__ k_lo,
    ushort* __restrict__ v_nat)
{
  const int i = blockIdx.x, j = i >> 3;
  const int tmb = (i & 7) * 8 + (j & 7);   // row-strip, XCD-grouped
  const int tn  = j >> 3;                  // col-panel [0,12)
  const int tid = threadIdx.x, lane = tid & 63, w = tid >> 6;
  const int col16 = lane & 15, quad = lane >> 4;
  const int wr = w >> 1, wc = w & 1;

  __shared__ short sbuf[16384];   // 32KB: hi@[buf*4096], lo@[8192+buf*4096]

  // per-thread global src offset within a chunk (bytes: w*2048 + lane*16)
  const int wl   = w * 1024 + lane * 8;    // ushorts
  const int ldsw = w * 1024;               // wave-uniform LDS offset (ushorts)
  const ushort* shp = wT_hi + (size_t)tn * 4096 + wl;
  const ushort* slp = wT_lo + (size_t)tn * 4096 + wl;

  const float*  axf[4];
  const ushort *axh[4], *axl[4];
#pragma unroll
  for (int rt = 0; rt < 4; ++rt) {
    const size_t rowoff = (size_t)(tmb * 128 + wr * 64 + rt * 16 + col16) * 512 + quad * 8;
    axf[rt] = x  + rowoff;
    axh[rt] = xh + rowoff;
    axl[rt] = xl + rowoff;
  }

  f32x4 acc[4][4];
#pragma unroll
  for (int rt = 0; rt < 4; ++rt)
#pragma unroll
    for (int ct = 0; ct < 4; ++ct) acc[rt][ct] = (f32x4){0.f, 0.f, 0.f, 0.f};

  // prologue: stage chunk 0 into buf 0
  gl_lds16(shp,       sbuf + ldsw);
  gl_lds16(shp + 512, sbuf + ldsw + 512);
  gl_lds16(slp,       sbuf + 8192 + ldsw);
  gl_lds16(slp + 512, sbuf + 8192 + ldsw + 512);
  __syncthreads();

  int buf = 0;
#pragma unroll
  for (int c = 0; c < 16; ++c) {
    if (c < 15) {                        // issue next-chunk stages (async)
      const size_t co = (size_t)(c + 1) * 49152;
      const int nb = (buf ^ 1) * 4096;
      gl_lds16(shp + co,       sbuf + nb + ldsw);
      gl_lds16(shp + co + 512, sbuf + nb + ldsw + 512);
      gl_lds16(slp + co,       sbuf + 8192 + nb + ldsw);
      gl_lds16(slp + co + 512, sbuf + 8192 + nb + ldsw + 512);
    }
    const int k0 = c * 32;
    const short* bhb = sbuf + buf * 4096;
    const short* blb = sbuf + 8192 + buf * 4096;

    bf16x8 bh[4], bl[4];
#pragma unroll
    for (int ct = 0; ct < 4; ++ct) {
      const int roff = (wc * 64 + ct * 16 + col16) * 32 + quad * 8;
      bh[ct] = *(const bf16x8*)(bhb + roff);
      bl[ct] = *(const bf16x8*)(blb + roff);
    }
#pragma unroll
    for (int rt = 0; rt < 4; ++rt) {
      bf16x8 a_hi, a_lo;
      if constexpr (PRECVT) {
        a_hi = *(const bf16x8*)(axh[rt] + k0);
        a_lo = *(const bf16x8*)(axl[rt] + k0);
      } else {
        float4 xa = *(const float4*)(axf[rt] + k0);
        float4 xb = *(const float4*)(axf[rt] + k0 + 4);
#pragma unroll
        for (int jj = 0; jj < 4; ++jj) {
          ushort h, l;
          split2(((const float*)&xa)[jj], h, l);
          ((short*)&a_hi)[jj] = (short)h; ((short*)&a_lo)[jj] = (short)l;
          split2(((const float*)&xb)[jj], h, l);
          ((short*)&a_hi)[4 + jj] = (short)h; ((short*)&a_lo)[4 + jj] = (short)l;
        }
      }
#pragma unroll
      for (int ct = 0; ct < 4; ++ct) {
        acc[rt][ct] = MFMA16(a_hi, bh[ct], acc[rt][ct]);
        acc[rt][ct] = MFMA16(a_hi, bl[ct], acc[rt][ct]);
        acc[rt][ct] = MFMA16(a_lo, bh[ct], acc[rt][ct]);
      }
    }
    __syncthreads();                     // drains in-flight stage + syncs
    buf ^= 1;
  }

  // ---- coalesced epilogue via wave-private LDS transpose (aliases sbuf) ----
  short* eph = sbuf + w * 2304;               // 16 rows x 72, hi plane
  short* epl = eph + 1152;                    // lo plane
  const int g0   = tn * 128 + wc * 64;        // wave-uniform 64-col block
  const int sect = (g0 % 192) >> 6;           // 0=q 1=k 2=v
  const int s    = g0 / 192;                  // n & 7
  float bv[4];
#pragma unroll
  for (int ct = 0; ct < 4; ++ct) bv[ct] = bqkv[g0 + ct * 16 + col16];

#pragma unroll
  for (int rt = 0; rt < 4; ++rt) {
#pragma unroll
    for (int ct = 0; ct < 4; ++ct) {
#pragma unroll
      for (int r = 0; r < 4; ++r) {
        const float val = acc[rt][ct][r] + bv[ct];
        const int o = (quad * 4 + r) * 72 + ct * 16 + col16;
        if (sect == 2) {
          eph[o] = (short)f2bf_rne(val);
        } else {
          ushort h, l; split2(val, h, l);
          eph[o] = (short)h; epl[o] = (short)l;
        }
      }
    }
#pragma unroll
    for (int p = 0; p < 2; ++p) {
      const int row = p * 8 + (lane >> 3);
      const int dsg = (lane & 7) * 8;
      const int grow = tmb * 128 + wr * 64 + rt * 16 + row;
      const int bhh = grow >> 8, a = grow & 255;
      const size_t idx = ((size_t)bhh * 2048 + 8 * a + s) * 64 + dsg;
      uint4 hv = *(const uint4*)(eph + row * 72 + dsg);
      if (sect == 0) {
        *(uint4*)(q_hi + idx) = hv;
        uint4 lv = *(const uint4*)(epl + row * 72 + dsg);
        *(uint4*)(q_lo + idx) = lv;
      } else if (sect == 1) {
        *(uint4*)(k_hi + idx) = hv;
        uint4 lv = *(const uint4*)(epl + row * 72 + dsg);
        *(uint4*)(k_lo + idx) = lv;
      } else {
        *(uint4*)(v_nat + idx) = hv;
      }
    }
  }
}

// ---------------------------------------------------------------------------
// K1b: v [bh][n][d] -> vT [bh][d][n].  Grid: 32 bh x 8 n-tiles(256) = 256.
// ---------------------------------------------------------------------------
__global__ __launch_bounds__(256) void vtrans_k(const ushort* __restrict__ v_nat,
                                                ushort* __restrict__ vT)
{
  const int t  = blockIdx.x & 7;
  const int bh = blockIdx.x >> 3;
  const int tid = threadIdx.x;
  const int nl = tid & 63;
  const int dg = tid >> 6;
  const size_t base = (size_t)bh * 2048 * 64;
#pragma unroll
  for (int p = 0; p < 2; ++p) {
    const int dseg = dg + p * 4;
#pragma unroll
    for (int nb = 0; nb < 4; ++nb) {
      const int n = t * 256 + nb * 64 + nl;
      uint4 vv = *(const uint4*)(v_nat + base + (size_t)n * 64 + dseg * 8);
      const ushort* pv = (const ushort*)&vv;
#pragma unroll
      for (int j = 0; j < 8; ++j)
        vT[base + (size_t)(dseg * 8 + j) * 2048 + n] = pv[j];
    }
  }
}

// ---------------------------------------------------------------------------
// K2: flash attention. R18 structure (swapped QK^T, packed softmax, scalar
// lsum) + R19 unroll x2 (buf compile-time). Block = 512 thr (8 waves),
// wave = 16 q-rows, grid 512. Proven 71.8us.
// ---------------------------------------------------------------------------
__global__ __launch_bounds__(512, 4) void attn_k(
    const ushort* __restrict__ q_hi, const ushort* __restrict__ q_lo,
    const ushort* __restrict__ k_hi, const ushort* __restrict__ k_lo,
    const ushort* __restrict__ vT, ushort* __restrict__ y)
{
  const int i  = blockIdx.x;
  const int bh = (i & 7) * 4 + (i >> 7);   // XCD-local bh group
  const int qt = (i >> 3) & 15;
  const int tid = threadIdx.x, lane = tid & 63, w = tid >> 6;  // w in [0,8)
  const int col16 = lane & 15, quad = lane >> 4;
  const int n7 = col16 & 7;

  // [buf][plane][4096]: kh, kl, vt planes of [64 rows][64 shorts], swizzled.
  // p at +24576: [wave8][16 q][64 k] granule-swizzled. 32768 shorts = 64KB.
  __shared__ short sbuf[32768];

  const size_t base = (size_t)bh * 2048 * 64;
  const int qw = qt * 128 + w * 16;        // wave-private 16 q-rows

  const ushort* khs = k_hi + base;
  const ushort* kls = k_lo + base;
  const ushort* vts = vT  + base;

  // per-lane staging geometry: lane covers LDS shorts [sub*512 + lane*8, +8)
  const int lrow = lane >> 3;               // row within 8-row group
  const int lx8  = ((lane & 7) ^ lrow) * 8; // inverse-swizzled 16B slot

  bf16x8 qh[2], ql[2];
#pragma unroll
  for (int ks = 0; ks < 2; ++ks) {
    const size_t off = base + (size_t)(qw + col16) * 64 + ks * 32 + quad * 8;
    qh[ks] = *(const bf16x8*)(q_hi + off);
    ql[ks] = *(const bf16x8*)(q_lo + off);
  }

  f32x4 oacc[4];
#pragma unroll
  for (int ct = 0; ct < 4; ++ct) oacc[ct] = (f32x4){0.f, 0.f, 0.f, 0.f};
  float lsum = 0.f;                        // scalar: q=col16 fixed per lane

  const float S2 = 11.541560327111707f;   // 8 * log2(e)

  short* wp0 = sbuf + 24576 + w * 1024;   // wave-private P: [16 q][64 k]

  // stage chunk cnext into buffer nb: 24 x 1KB blocks, 3 per wave
#define STAGE_CHUNK(cnext, nb)                                                \
  {                                                                           \
    _Pragma("unroll")                                                         \
    for (int ii = 0; ii < 3; ++ii) {                                          \
      const int ins = w * 3 + ii;                                             \
      const int plane = ins >> 3, sub = ins & 7;                              \
      short* dst = sbuf + ((nb) * 3 + plane) * 4096 + sub * 512;              \
      const ushort* src;                                                      \
      if (plane == 2)                                                         \
        src = vts + (size_t)(sub * 8 + lrow) * 2048 + (cnext) * 64 + lx8;     \
      else                                                                    \
        src = (plane ? kls : khs) + (cnext) * 4096 + sub * 512 + lrow * 64 + lx8; \
      gl_lds16(src, dst);                                                     \
    }                                                                         \
  }

  // one chunk body; BUF is a compile-time constant (0/1)
#define ATTN_CHUNK(C, BUF)                                                    \
  {                                                                           \
    if ((C) < 31) STAGE_CHUNK((C) + 1, (BUF) ^ 1);                            \
    const short* kb = sbuf + ((BUF) * 3) * 4096;                              \
    const short* lb = kb + 4096;                                              \
    const short* vb = kb + 8192;                                              \
    f32x4 sacc[4];                                                            \
    _Pragma("unroll")                                                         \
    for (int ct = 0; ct < 4; ++ct) sacc[ct] = (f32x4){0.f, 0.f, 0.f, 0.f};    \
    __builtin_amdgcn_s_setprio(1);                                            \
    _Pragma("unroll")                                                         \
    for (int ks = 0; ks < 2; ++ks) {                                          \
      _Pragma("unroll")                                                       \
      for (int ct = 0; ct < 4; ++ct) {                                        \
        const int off = (ct * 16 + col16) * 64 + (((ks * 4 + quad) ^ n7) << 3); \
        bf16x8 khf = *(const bf16x8*)(kb + off);                              \
        bf16x8 klf = *(const bf16x8*)(lb + off);                              \
        sacc[ct] = MFMA16(khf, qh[ks], sacc[ct]);                             \
        sacc[ct] = MFMA16(klf, qh[ks], sacc[ct]);                             \
        sacc[ct] = MFMA16(khf, ql[ks], sacc[ct]);                             \
      }                                                                       \
    }                                                                         \
    __builtin_amdgcn_s_setprio(0);                                            \
    _Pragma("unroll")                                                         \
    for (int ct = 0; ct < 4; ++ct) {                                          \
      union { float f; unsigned u; } p0, p1, p2, p3;                          \
      p0.f = __builtin_amdgcn_exp2f(fmaf(sacc[ct][0], S2, -128.0f));          \
      p1.f = __builtin_amdgcn_exp2f(fmaf(sacc[ct][1], S2, -128.0f));          \
      p2.f = __builtin_amdgcn_exp2f(fmaf(sacc[ct][2], S2, -128.0f));          \
      p3.f = __builtin_amdgcn_exp2f(fmaf(sacc[ct][3], S2, -128.0f));          \
      lsum += (p0.f + p1.f) + (p2.f + p3.f);                                  \
      const unsigned lo = (p0.u >> 16) | (p1.u & 0xffff0000u);                \
      const unsigned hi = (p2.u >> 16) | (p3.u & 0xffff0000u);                \
      const int g8 = (ct * 2 + (quad >> 1)) ^ n7;                             \
      uint2 pk; pk.x = lo; pk.y = hi;                                         \
      *(uint2*)(wp0 + col16 * 64 + (g8 << 3) + ((quad & 1) << 2)) = pk;       \
    }                                                                         \
    __builtin_amdgcn_s_setprio(1);                                            \
    _Pragma("unroll")                                                         \
    for (int ks = 0; ks < 2; ++ks) {                                          \
      bf16x8 ap = *(const bf16x8*)(wp0 + col16 * 64 +                         \
                                   (((ks * 4 + quad) ^ n7) << 3));            \
      _Pragma("unroll")                                                       \
      for (int ct = 0; ct < 4; ++ct) {                                        \
        const int voff = (ct * 16 + col16) * 64 + (((ks * 4 + quad) ^ n7) << 3); \
        bf16x8 vv = *(const bf16x8*)(vb + voff);                              \
        oacc[ct] = MFMA16(ap, vv, oacc[ct]);                                  \
      }                                                                       \
    }                                                                         \
    __builtin_amdgcn_s_setprio(0);                                            \
    __syncthreads();                                                          \
  }

  STAGE_CHUNK(0, 0);
  __syncthreads();

  for (int c = 0; c < 32; c += 2) {      // unrolled x2: BUF compile-time
    ATTN_CHUNK(c, 0);
    ATTN_CHUNK(c + 1, 1);
  }

  // epilogue: lsum covers quads' k-partials -> reduce over quads, then
  // fetch per-output-row inv via dynamic shuffle (row q lives at lane q).
  lsum += __shfl_xor(lsum, 16, 64);
  lsum += __shfl_xor(lsum, 32, 64);
#pragma unroll
  for (int r = 0; r < 4; ++r) {
    const float inv = 1.f / __shfl(lsum, quad * 4 + r, 64);
    const int n = qw + quad * 4 + r;
    const size_t orow = ((size_t)bh * 256 + (n >> 3)) * 512 + (n & 7) * 64;
#pragma unroll
    for (int ct = 0; ct < 4; ++ct)
      y[orow + ct * 16 + col16] = f2bf_rne(oacc[ct][r] * inv);
  }
#undef ATTN_CHUNK
#undef STAGE_CHUNK
}

// ---------------------------------------------------------------------------
// K3: out = y @ Wo + bo, 32x128 tiles (plain bf16 MFMA, f32 out). Grid 1024
// (4 blocks/CU), XCD-swizzled. Wave = 16 rows x 64 cols. R21: B staged via
// gl_lds16 from chunked woT (R14 template), LDS 20->16KB linear dbuf.
// ---------------------------------------------------------------------------
__global__ __launch_bounds__(256) void out_gemm_k(
    const ushort* __restrict__ y, const ushort* __restrict__ woT,
    const float* __restrict__ bo, float* __restrict__ out)
{
  const int i = blockIdx.x, j = i >> 3;
  const int tmb = (i & 7) * 32 + (j & 31);  // 256 row-strips of 32, XCD-grouped
  const int tn  = j >> 5;                   // [0,4) col-panel of 128
  const int tid = threadIdx.x, lane = tid & 63, w = tid >> 6;
  const int col16 = lane & 15, quad = lane >> 4;
  const int wr = w >> 1, wc = w & 1;

  __shared__ short sb[8192];   // 16KB: [buf][128 rows][32 ks] linear

  // per-thread staging: 8KB/chunk = 8 x 1KB, 2 per wave
  const ushort* bch = woT + (size_t)tn * 4096 + lane * 8;

  const ushort* ay = y + (size_t)(tmb * 32 + wr * 16 + col16) * 512 + quad * 8;

  f32x4 acc[4];
#pragma unroll
  for (int ct = 0; ct < 4; ++ct) acc[ct] = (f32x4){0.f, 0.f, 0.f, 0.f};

#define OSTAGE(cn, nb)                                                        \
  {                                                                           \
    _Pragma("unroll")                                                         \
    for (int ii = 0; ii < 2; ++ii) {                                          \
      const int ins = w * 2 + ii;                                             \
      gl_lds16(bch + (size_t)(cn) * 16384 + ins * 512,                        \
               sb + (nb) * 4096 + ins * 512);                                 \
    }                                                                         \
  }

  OSTAGE(0, 0);
  __syncthreads();

  int buf = 0;
#pragma unroll
  for (int c = 0; c < 16; ++c) {
    if (c < 15) OSTAGE(c + 1, buf ^ 1);   // async, lands before barrier
    const int k0 = c * 32;
    const short* bb = sb + buf * 4096;
    bf16x8 af = *(const bf16x8*)(ay + k0);
#pragma unroll
    for (int ct = 0; ct < 4; ++ct) {
      const int roff = (wc * 64 + ct * 16 + col16) * 32 + quad * 8;
      bf16x8 bfr = *(const bf16x8*)(bb + roff);
      acc[ct] = MFMA16(af, bfr, acc[ct]);
    }
    __syncthreads();                     // drains in-flight stage + syncs
    buf ^= 1;
  }
#undef OSTAGE

#pragma unroll
  for (int ct = 0; ct < 4; ++ct) {
    const int col = tn * 128 + wc * 64 + ct * 16 + col16;
    const float bval = bo[col];
#pragma unroll
    for (int r = 0; r < 4; ++r) {
      const int row = tmb * 32 + wr * 16 + quad * 4 + r;
      out[(size_t)row * 512 + col] = acc[ct][r] + bval;
    }
  }
}

// ---------------------------------------------------------------------------
extern "C" void kernel_launch(void* const* d_in, const int* in_sizes, int n_in,
                              void* d_out, int out_size, void* d_ws, size_t ws_size,
                              hipStream_t stream)
{
  const float* x    = (const float*)d_in[0];
  const float* Wqkv = (const float*)d_in[1];
  const float* bqkv = (const float*)d_in[2];
  const float* Wo   = (const float*)d_in[3];
  const float* bo   = (const float*)d_in[4];
  float* out = (float*)d_out;

  // ws (ushort elems). Base (R6-proven, 54.0 MB): weights + q/k/v planes.
  ushort* wT_hi = (ushort*)d_ws;                    //  786432 (chunked layout)
  ushort* wT_lo = wT_hi + 786432;                   //  786432
  ushort* woT   = wT_lo + 786432;                   //  262144 (chunked layout)
  ushort* q_hi  = woT   + 262144;                   // 4194304 each below
  ushort* q_lo  = q_hi  + 4194304;
  ushort* k_hi  = q_lo  + 4194304;
  ushort* k_lo  = k_hi  + 4194304;
  ushort* v_nat = k_lo  + 4194304;
  ushort* tail  = v_nat + 4194304;

  // Roomy path (62.4 MB): xh/xl planes; vT aliases xh, y aliases xl (both
  // dead after K1). ws_size is launch-invariant -> stable graph capture.
  const bool roomy = ws_size >= 62390272ULL;
  ushort *xh, *xl, *vT, *y;
  if (roomy) {
    xh = tail; xl = tail + 4194304;
    vT = xh;   y  = xl;                 // reused post-K1
  } else {
    xh = xl = nullptr;
    vT = tail; y = v_nat;               // R6 mapping (54.0 MB, proven)
  }

  if (roomy) {
    cvt_k<true><<<8192, 256, 0, stream>>>(Wqkv, Wo, x, wT_hi, wT_lo, woT, xh, xl);
    qkv_gemm_k<true><<<768, 256, 0, stream>>>(x, xh, xl, wT_hi, wT_lo, bqkv,
                                              q_hi, q_lo, k_hi, k_lo, v_nat);
  } else {
    cvt_k<false><<<4096, 256, 0, stream>>>(Wqkv, Wo, x, wT_hi, wT_lo, woT,
                                           nullptr, nullptr);
    qkv_gemm_k<false><<<768, 256, 0, stream>>>(x, nullptr, nullptr, wT_hi, wT_lo,
                                               bqkv, q_hi, q_lo, k_hi, k_lo, v_nat);
  }
  vtrans_k<<<256, 256, 0, stream>>>(v_nat, vT);
  attn_k<<<512, 512, 0, stream>>>(q_hi, q_lo, k_hi, k_lo, vT, y);
  out_gemm_k<<<1024, 256, 0, stream>>>(y, woT, bo, out);
}

// Round 11
// 221.209 us; speedup vs baseline: 1.0515x; 1.0063x over previous
//
#include <hip/hip_runtime.h>
#include <hip/hip_bf16.h>
#include <math.h>

// ---------------------------------------------------------------------------
// MultiHeadSelfAttention  B=4 N=2048 E=512 H=8 DK=DV=64   (f32 in / f32 out)
// Split-bf16 (hi/lo) MFMA on the attention-critical path.
//
// Reference quirks (verified passing):
//  * qkv.reshape(B,H,N,192) is token-mixing: with GEMM col g:
//    s=g/192, sect=(g%192)/64, d=g%64, n=8a+s (a=row%256, bh=row/256).
//  * y.reshape: y[b,h,n,d] -> yws[bh*256 + (n>>3)][(n&7)*64 + d]
//  * qk / DK**-0.5 == qk * 8.0
//
// R21 post-mortem: out_gemm gl_lds staging gained only ~1us (it was already
// cheap). attn stable 73.7us (structural floor). Re-audit of the invisible
// ~149us: cvt_k's weight paths read wqkv/wo at stride 6KB/2KB (4B used per
// 128B line, 64 lines/wave-load) -> est. 20-30us for a ~6us job.
//
// R22 (this round):
//  * cvt_k REWRITTEN with LDS-tiled transpose (32k x 128n tiles, 256 blocks
//    for weights): coalesced float4 row reads -> split -> LDS [n][k] stride
//    40 (80B rows, 16B-aligned) -> coalesced uint4 chunked writes. Output
//    bytes BIT-IDENTICAL (same split2/f2bf_rne on same values).
//  * vtrans grid 256 -> 1024 (was 1 block/CU, latency-bound; coalesced
//    otherwise). Same elements written once each.
//  * qkv/attn/out_gemm byte-identical.
// ---------------------------------------------------------------------------

typedef __attribute__((ext_vector_type(8))) short bf16x8;
typedef __attribute__((ext_vector_type(4))) float f32x4;

#define MFMA16(a, b, c) __builtin_amdgcn_mfma_f32_16x16x32_bf16((a), (b), (c), 0, 0, 0)

__device__ __forceinline__ ushort f2bf_rne(float f) {
  union { float f; unsigned u; } v; v.f = f;
  return (ushort)((v.u + 0x7fffu + ((v.u >> 16) & 1u)) >> 16);
}
__device__ __forceinline__ float bf2f(ushort h) {
  union { float f; unsigned u; } v; v.u = ((unsigned)h) << 16; return v.f;
}
__device__ __forceinline__ void split2(float f, ushort& hi, ushort& lo) {
  union { float f; unsigned u; } v; v.f = f;
  hi = (ushort)(v.u >> 16);
  union { float f; unsigned u; } r; r.f = f - bf2f(hi);
  lo = (ushort)(r.u >> 16);          // trunc lo: rel err ~2^-16.5, negligible
}

// async global->LDS, 16B per lane; lds ptr must be wave-uniform (HW adds lane*16)
typedef __attribute__((address_space(3))) unsigned int lds_uint;
typedef const __attribute__((address_space(1))) unsigned int glob_uint;
__device__ __forceinline__ void gl_lds16(const ushort* g, short* l) {
  __builtin_amdgcn_global_load_lds((glob_uint*)g, (lds_uint*)l, 16, 0, 0);
}

// ---------------------------------------------------------------------------
// K0 (fused, R22 LDS-tiled): blocks 0..191: wqkv -> wT_hi/lo chunked
// [c16][n1536][ks32]; blocks 192..255: wo -> woT chunked [c16][n512][ks32];
// blocks 256.. (ROOMY): x -> xh/xl bf16 planes (already coalesced).
// Weight tiles: 32k x 128n; phase1 coalesced float4 reads + LDS [n][k]
// scatter (stride 40 shorts = 80B, 16B-aligned); phase2 coalesced uint4
// writes (2KB contiguous per wave).
// ---------------------------------------------------------------------------
template <bool ROOMY>
__global__ __launch_bounds__(256) void cvt_k(const float* __restrict__ wqkv,
                                             const float* __restrict__ wo,
                                             const float* __restrict__ x,
                                             ushort* __restrict__ wT_hi,
                                             ushort* __restrict__ wT_lo,
                                             ushort* __restrict__ woT,
                                             ushort* __restrict__ xh,
                                             ushort* __restrict__ xl)
{
  const int bid = blockIdx.x, tid = threadIdx.x;
  if (bid < 256) {
    __shared__ short lh[128 * 40], ll[128 * 40];   // 20 KB
    const bool isW1 = bid < 192;
    const int c  = isW1 ? (bid / 12) : ((bid - 192) >> 2);   // k-chunk 0..15
    const int nt = isW1 ? (bid % 12) : ((bid - 192) & 3);    // n-tile of 128
    const int NN = isW1 ? 1536 : 512;
    const float* src = isW1 ? wqkv : wo;

    // phase 1: read 32k x 128n coalesced, convert, scatter to LDS [n][k]
    const int kl = tid >> 3;             // 0..31 (k within chunk)
    const int n0 = (tid & 7) * 16;       // 0..112
    const float* rp = src + (size_t)(c * 32 + kl) * NN + nt * 128 + n0;
#pragma unroll
    for (int q = 0; q < 4; ++q) {
      float4 v = *(const float4*)(rp + q * 4);
#pragma unroll
      for (int e = 0; e < 4; ++e) {
        const int nl = n0 + q * 4 + e;
        const float f = ((const float*)&v)[e];
        if (isW1) {
          ushort h, l; split2(f, h, l);
          lh[nl * 40 + kl] = (short)h;
          ll[nl * 40 + kl] = (short)l;
        } else {
          lh[nl * 40 + kl] = (short)f2bf_rne(f);
        }
      }
    }
    __syncthreads();

    // phase 2: write chunked layout, fully coalesced (thread = 32B run)
    const int n2 = tid >> 1;                 // 0..127
    const int half = (tid & 1) * 16;         // 0 or 16 shorts
    if (isW1) {
      const size_t ob = (size_t)c * 49152 + (size_t)(nt * 128 + n2) * 32 + half;
      *(uint4*)(wT_hi + ob)     = *(const uint4*)(lh + n2 * 40 + half);
      *(uint4*)(wT_hi + ob + 8) = *(const uint4*)(lh + n2 * 40 + half + 8);
      *(uint4*)(wT_lo + ob)     = *(const uint4*)(ll + n2 * 40 + half);
      *(uint4*)(wT_lo + ob + 8) = *(const uint4*)(ll + n2 * 40 + half + 8);
    } else {
      const size_t ob = (size_t)c * 16384 + (size_t)(nt * 128 + n2) * 32 + half;
      *(uint4*)(woT + ob)     = *(const uint4*)(lh + n2 * 40 + half);
      *(uint4*)(woT + ob + 8) = *(const uint4*)(lh + n2 * 40 + half + 8);
    }
  } else if (ROOMY) {
    const int g = (bid - 256) * 256 + tid;   // [0, 1048576) vec4 slots
    float4 v = ((const float4*)x)[g];
    ushort4 hh, llv;
    split2(v.x, hh.x, llv.x); split2(v.y, hh.y, llv.y);
    split2(v.z, hh.z, llv.z); split2(v.w, hh.w, llv.w);
    ((ushort4*)xh)[g] = hh;
    ((ushort4*)xl)[g] = llv;
  }
}

// ---------------------------------------------------------------------------
// K1: qkv GEMM, 128x128 tile/block (4 waves 2x2, wave = 64x64 = 4x4 acc).
// B staged via global_load_lds(16B) from chunked wT (R14, proven).
// ---------------------------------------------------------------------------
template <bool PRECVT>
__global__ __launch_bounds__(256) void qkv_gemm_k(
    const float* __restrict__ x,
    const ushort* __restrict__ xh, const ushort* __restrict__ xl,
    const ushort* __restrict__ wT_hi, const ushort* __restrict__ wT_lo,
    const float* __restrict__ bqkv,
    ushort* __restrict__ q_hi, ushort* __restrict__ q_lo,
    ushort* __restrict__ k_hi, ushort* __restrict__ k_lo,
    ushort* __restrict__ v_nat)
{
  const int i = blockIdx.x, j = i >> 3;
  const int tmb = (i & 7) * 8 + (j & 7);   // row-strip, XCD-grouped
  const int tn  = j >> 3;                  // col-panel [0,12)
  const int tid = threadIdx.x, lane = tid & 63, w = tid >> 6;
  const int col16 = lane & 15, quad = lane >> 4;
  const int wr = w >> 1, wc = w & 1;

  __shared__ short sbuf[16384];   // 32KB: hi@[buf*4096], lo@[8192+buf*4096]

  // per-thread global src offset within a chunk (bytes: w*2048 + lane*16)
  const int wl   = w * 1024 + lane * 8;    // ushorts
  const int ldsw = w * 1024;               // wave-uniform LDS offset (ushorts)
  const ushort* shp = wT_hi + (size_t)tn * 4096 + wl;
  const ushort* slp = wT_lo + (size_t)tn * 4096 + wl;

  const float*  axf[4];
  const ushort *axh[4], *axl[4];
#pragma unroll
  for (int rt = 0; rt < 4; ++rt) {
    const size_t rowoff = (size_t)(tmb * 128 + wr * 64 + rt * 16 + col16) * 512 + quad * 8;
    axf[rt] = x  + rowoff;
    axh[rt] = xh + rowoff;
    axl[rt] = xl + rowoff;
  }

  f32x4 acc[4][4];
#pragma unroll
  for (int rt = 0; rt < 4; ++rt)
#pragma unroll
    for (int ct = 0; ct < 4; ++ct) acc[rt][ct] = (f32x4){0.f, 0.f, 0.f, 0.f};

  // prologue: stage chunk 0 into buf 0
  gl_lds16(shp,       sbuf + ldsw);
  gl_lds16(shp + 512, sbuf + ldsw + 512);
  gl_lds16(slp,       sbuf + 8192 + ldsw);
  gl_lds16(slp + 512, sbuf + 8192 + ldsw + 512);
  __syncthreads();

  int buf = 0;
#pragma unroll
  for (int c = 0; c < 16; ++c) {
    if (c < 15) {                        // issue next-chunk stages (async)
      const size_t co = (size_t)(c + 1) * 49152;
      const int nb = (buf ^ 1) * 4096;
      gl_lds16(shp + co,       sbuf + nb + ldsw);
      gl_lds16(shp + co + 512, sbuf + nb + ldsw + 512);
      gl_lds16(slp + co,       sbuf + 8192 + nb + ldsw);
      gl_lds16(slp + co + 512, sbuf + 8192 + nb + ldsw + 512);
    }
    const int k0 = c * 32;
    const short* bhb = sbuf + buf * 4096;
    const short* blb = sbuf + 8192 + buf * 4096;

    bf16x8 bh[4], bl[4];
#pragma unroll
    for (int ct = 0; ct < 4; ++ct) {
      const int roff = (wc * 64 + ct * 16 + col16) * 32 + quad * 8;
      bh[ct] = *(const bf16x8*)(bhb + roff);
      bl[ct] = *(const bf16x8*)(blb + roff);
    }
#pragma unroll
    for (int rt = 0; rt < 4; ++rt) {
      bf16x8 a_hi, a_lo;
      if constexpr (PRECVT) {
        a_hi = *(const bf16x8*)(axh[rt] + k0);
        a_lo = *(const bf16x8*)(axl[rt] + k0);
      } else {
        float4 xa = *(const float4*)(axf[rt] + k0);
        float4 xb = *(const float4*)(axf[rt] + k0 + 4);
#pragma unroll
        for (int jj = 0; jj < 4; ++jj) {
          ushort h, l;
          split2(((const float*)&xa)[jj], h, l);
          ((short*)&a_hi)[jj] = (short)h; ((short*)&a_lo)[jj] = (short)l;
          split2(((const float*)&xb)[jj], h, l);
          ((short*)&a_hi)[4 + jj] = (short)h; ((short*)&a_lo)[4 + jj] = (short)l;
        }
      }
#pragma unroll
      for (int ct = 0; ct < 4; ++ct) {
        acc[rt][ct] = MFMA16(a_hi, bh[ct], acc[rt][ct]);
        acc[rt][ct] = MFMA16(a_hi, bl[ct], acc[rt][ct]);
        acc[rt][ct] = MFMA16(a_lo, bh[ct], acc[rt][ct]);
      }
    }
    __syncthreads();                     // drains in-flight stage + syncs
    buf ^= 1;
  }

  // ---- coalesced epilogue via wave-private LDS transpose (aliases sbuf) ----
  short* eph = sbuf + w * 2304;               // 16 rows x 72, hi plane
  short* epl = eph + 1152;                    // lo plane
  const int g0   = tn * 128 + wc * 64;        // wave-uniform 64-col block
  const int sect = (g0 % 192) >> 6;           // 0=q 1=k 2=v
  const int s    = g0 / 192;                  // n & 7
  float bv[4];
#pragma unroll
  for (int ct = 0; ct < 4; ++ct) bv[ct] = bqkv[g0 + ct * 16 + col16];

#pragma unroll
  for (int rt = 0; rt < 4; ++rt) {
#pragma unroll
    for (int ct = 0; ct < 4; ++ct) {
#pragma unroll
      for (int r = 0; r < 4; ++r) {
        const float val = acc[rt][ct][r] + bv[ct];
        const int o = (quad * 4 + r) * 72 + ct * 16 + col16;
        if (sect == 2) {
          eph[o] = (short)f2bf_rne(val);
        } else {
          ushort h, l; split2(val, h, l);
          eph[o] = (short)h; epl[o] = (short)l;
        }
      }
    }
#pragma unroll
    for (int p = 0; p < 2; ++p) {
      const int row = p * 8 + (lane >> 3);
      const int dsg = (lane & 7) * 8;
      const int grow = tmb * 128 + wr * 64 + rt * 16 + row;
      const int bhh = grow >> 8, a = grow & 255;
      const size_t idx = ((size_t)bhh * 2048 + 8 * a + s) * 64 + dsg;
      uint4 hv = *(const uint4*)(eph + row * 72 + dsg);
      if (sect == 0) {
        *(uint4*)(q_hi + idx) = hv;
        uint4 lv = *(const uint4*)(epl + row * 72 + dsg);
        *(uint4*)(q_lo + idx) = lv;
      } else if (sect == 1) {
        *(uint4*)(k_hi + idx) = hv;
        uint4 lv = *(const uint4*)(epl + row * 72 + dsg);
        *(uint4*)(k_lo + idx) = lv;
      } else {
        *(uint4*)(v_nat + idx) = hv;
      }
    }
  }
}

// ---------------------------------------------------------------------------
// K1b: v [bh][n][d] -> vT [bh][d][n].  R22: grid 1024 (was 256, 1 block/CU
// latency-bound). bid = bh*32 + t*4 + nb; each block does one 64-n slab.
// ---------------------------------------------------------------------------
__global__ __launch_bounds__(256) void vtrans_k(const ushort* __restrict__ v_nat,
                                                ushort* __restrict__ vT)
{
  const int bid = blockIdx.x;
  const int bh = bid >> 5;
  const int t  = (bid >> 2) & 7;
  const int nb = bid & 3;
  const int tid = threadIdx.x;
  const int nl = tid & 63;
  const int dg = tid >> 6;
  const size_t base = (size_t)bh * 2048 * 64;
  const int n = t * 256 + nb * 64 + nl;
#pragma unroll
  for (int p = 0; p < 2; ++p) {
    const int dseg = dg + p * 4;
    uint4 vv = *(const uint4*)(v_nat + base + (size_t)n * 64 + dseg * 8);
    const ushort* pv = (const ushort*)&vv;
#pragma unroll
    for (int j = 0; j < 8; ++j)
      vT[base + (size_t)(dseg * 8 + j) * 2048 + n] = pv[j];
  }
}

// ---------------------------------------------------------------------------
// K2: flash attention. R18 structure (swapped QK^T, packed softmax, scalar
// lsum) + R19 unroll x2 (buf compile-time). Block = 512 thr (8 waves),
// wave = 16 q-rows, grid 512. Proven 71.8us.
// ---------------------------------------------------------------------------
__global__ __launch_bounds__(512, 4) void attn_k(
    const ushort* __restrict__ q_hi, const ushort* __restrict__ q_lo,
    const ushort* __restrict__ k_hi, const ushort* __restrict__ k_lo,
    const ushort* __restrict__ vT, ushort* __restrict__ y)
{
  const int i  = blockIdx.x;
  const int bh = (i & 7) * 4 + (i >> 7);   // XCD-local bh group
  const int qt = (i >> 3) & 15;
  const int tid = threadIdx.x, lane = tid & 63, w = tid >> 6;  // w in [0,8)
  const int col16 = lane & 15, quad = lane >> 4;
  const int n7 = col16 & 7;

  // [buf][plane][4096]: kh, kl, vt planes of [64 rows][64 shorts], swizzled.
  // p at +24576: [wave8][16 q][64 k] granule-swizzled. 32768 shorts = 64KB.
  __shared__ short sbuf[32768];

  const size_t base = (size_t)bh * 2048 * 64;
  const int qw = qt * 128 + w * 16;        // wave-private 16 q-rows

  const ushort* khs = k_hi + base;
  const ushort* kls = k_lo + base;
  const ushort* vts = vT  + base;

  // per-lane staging geometry: lane covers LDS shorts [sub*512 + lane*8, +8)
  const int lrow = lane >> 3;               // row within 8-row group
  const int lx8  = ((lane & 7) ^ lrow) * 8; // inverse-swizzled 16B slot

  bf16x8 qh[2], ql[2];
#pragma unroll
  for (int ks = 0; ks < 2; ++ks) {
    const size_t off = base + (size_t)(qw + col16) * 64 + ks * 32 + quad * 8;
    qh[ks] = *(const bf16x8*)(q_hi + off);
    ql[ks] = *(const bf16x8*)(q_lo + off);
  }

  f32x4 oacc[4];
#pragma unroll
  for (int ct = 0; ct < 4; ++ct) oacc[ct] = (f32x4){0.f, 0.f, 0.f, 0.f};
  float lsum = 0.f;                        // scalar: q=col16 fixed per lane

  const float S2 = 11.541560327111707f;   // 8 * log2(e)

  short* wp0 = sbuf + 24576 + w * 1024;   // wave-private P: [16 q][64 k]

  // stage chunk cnext into buffer nb: 24 x 1KB blocks, 3 per wave
#define STAGE_CHUNK(cnext, nb)                                                \
  {                                                                           \
    _Pragma("unroll")                                                         \
    for (int ii = 0; ii < 3; ++ii) {                                          \
      const int ins = w * 3 + ii;                                             \
      const int plane = ins >> 3, sub = ins & 7;                              \
      short* dst = sbuf + ((nb) * 3 + plane) * 4096 + sub * 512;              \
      const ushort* src;                                                      \
      if (plane == 2)                                                         \
        src = vts + (size_t)(sub * 8 + lrow) * 2048 + (cnext) * 64 + lx8;     \
      else                                                                    \
        src = (plane ? kls : khs) + (cnext) * 4096 + sub * 512 + lrow * 64 + lx8; \
      gl_lds16(src, dst);                                                     \
    }                                                                         \
  }

  // one chunk body; BUF is a compile-time constant (0/1)
#define ATTN_CHUNK(C, BUF)                                                    \
  {                                                                           \
    if ((C) < 31) STAGE_CHUNK((C) + 1, (BUF) ^ 1);                            \
    const short* kb = sbuf + ((BUF) * 3) * 4096;                              \
    const short* lb = kb + 4096;                                              \
    const short* vb = kb + 8192;                                              \
    f32x4 sacc[4];                                                            \
    _Pragma("unroll")                                                         \
    for (int ct = 0; ct < 4; ++ct) sacc[ct] = (f32x4){0.f, 0.f, 0.f, 0.f};    \
    __builtin_amdgcn_s_setprio(1);                                            \
    _Pragma("unroll")                                                         \
    for (int ks = 0; ks < 2; ++ks) {                                          \
      _Pragma("unroll")                                                       \
      for (int ct = 0; ct < 4; ++ct) {                                        \
        const int off = (ct * 16 + col16) * 64 + (((ks * 4 + quad) ^ n7) << 3); \
        bf16x8 khf = *(const bf16x8*)(kb + off);                              \
        bf16x8 klf = *(const bf16x8*)(lb + off);                              \
        sacc[ct] = MFMA16(khf, qh[ks], sacc[ct]);                             \
        sacc[ct] = MFMA16(klf, qh[ks], sacc[ct]);                             \
        sacc[ct] = MFMA16(khf, ql[ks], sacc[ct]);                             \
      }                                                                       \
    }                                                                         \
    __builtin_amdgcn_s_setprio(0);                                            \
    _Pragma("unroll")                                                         \
    for (int ct = 0; ct < 4; ++ct) {                                          \
      union { float f; unsigned u; } p0, p1, p2, p3;                          \
      p0.f = __builtin_amdgcn_exp2f(fmaf(sacc[ct][0], S2, -128.0f));          \
      p1.f = __builtin_amdgcn_exp2f(fmaf(sacc[ct][1], S2, -128.0f));          \
      p2.f = __builtin_amdgcn_exp2f(fmaf(sacc[ct][2], S2, -128.0f));          \
      p3.f = __builtin_amdgcn_exp2f(fmaf(sacc[ct][3], S2, -128.0f));          \
      lsum += (p0.f + p1.f) + (p2.f + p3.f);                                  \
      const unsigned lo = (p0.u >> 16) | (p1.u & 0xffff0000u);                \
      const unsigned hi = (p2.u >> 16) | (p3.u & 0xffff0000u);                \
      const int g8 = (ct * 2 + (quad >> 1)) ^ n7;                             \
      uint2 pk; pk.x = lo; pk.y = hi;                                         \
      *(uint2*)(wp0 + col16 * 64 + (g8 << 3) + ((quad & 1) << 2)) = pk;       \
    }                                                                         \
    __builtin_amdgcn_s_setprio(1);                                            \
    _Pragma("unroll")                                                         \
    for (int ks = 0; ks < 2; ++ks) {                                          \
      bf16x8 ap = *(const bf16x8*)(wp0 + col16 * 64 +                         \
                                   (((ks * 4 + quad) ^ n7) << 3));            \
      _Pragma("unroll")                                                       \
      for (int ct = 0; ct < 4; ++ct) {                                        \
        const int voff = (ct * 16 + col16) * 64 + (((ks * 4 + quad) ^ n7) << 3); \
        bf16x8 vv = *(const bf16x8*)(vb + voff);                              \
        oacc[ct] = MFMA16(ap, vv, oacc[ct]);                                  \
      }                                                                       \
    }                                                                         \
    __builtin_amdgcn_s_setprio(0);                                            \
    __syncthreads();                                                          \
  }

  STAGE_CHUNK(0, 0);
  __syncthreads();

  for (int c = 0; c < 32; c += 2) {      // unrolled x2: BUF compile-time
    ATTN_CHUNK(c, 0);
    ATTN_CHUNK(c + 1, 1);
  }

  // epilogue: lsum covers quads' k-partials -> reduce over quads, then
  // fetch per-output-row inv via dynamic shuffle (row q lives at lane q).
  lsum += __shfl_xor(lsum, 16, 64);
  lsum += __shfl_xor(lsum, 32, 64);
#pragma unroll
  for (int r = 0; r < 4; ++r) {
    const float inv = 1.f / __shfl(lsum, quad * 4 + r, 64);
    const int n = qw + quad * 4 + r;
    const size_t orow = ((size_t)bh * 256 + (n >> 3)) * 512 + (n & 7) * 64;
#pragma unroll
    for (int ct = 0; ct < 4; ++ct)
      y[orow + ct * 16 + col16] = f2bf_rne(oacc[ct][r] * inv);
  }
#undef ATTN_CHUNK
#undef STAGE_CHUNK
}

// ---------------------------------------------------------------------------
// K3: out = y @ Wo + bo, 32x128 tiles (plain bf16 MFMA, f32 out). Grid 1024
// (4 blocks/CU), XCD-swizzled. Wave = 16 rows x 64 cols. B staged via
// gl_lds16 from chunked woT (R21), LDS 16KB linear dbuf.
// ---------------------------------------------------------------------------
__global__ __launch_bounds__(256) void out_gemm_k(
    const ushort* __restrict__ y, const ushort* __restrict__ woT,
    const float* __restrict__ bo, float* __restrict__ out)
{
  const int i = blockIdx.x, j = i >> 3;
  const int tmb = (i & 7) * 32 + (j & 31);  // 256 row-strips of 32, XCD-grouped
  const int tn  = j >> 5;                   // [0,4) col-panel of 128
  const int tid = threadIdx.x, lane = tid & 63, w = tid >> 6;
  const int col16 = lane & 15, quad = lane >> 4;
  const int wr = w >> 1, wc = w & 1;

  __shared__ short sb[8192];   // 16KB: [buf][128 rows][32 ks] linear

  // per-thread staging: 8KB/chunk = 8 x 1KB, 2 per wave
  const ushort* bch = woT + (size_t)tn * 4096 + lane * 8;

  const ushort* ay = y + (size_t)(tmb * 32 + wr * 16 + col16) * 512 + quad * 8;

  f32x4 acc[4];
#pragma unroll
  for (int ct = 0; ct < 4; ++ct) acc[ct] = (f32x4){0.f, 0.f, 0.f, 0.f};

#define OSTAGE(cn, nb)                                                        \
  {                                                                           \
    _Pragma("unroll")                                                         \
    for (int ii = 0; ii < 2; ++ii) {                                          \
      const int ins = w * 2 + ii;                                             \
      gl_lds16(bch + (size_t)(cn) * 16384 + ins * 512,                        \
               sb + (nb) * 4096 + ins * 512);                                 \
    }                                                                         \
  }

  OSTAGE(0, 0);
  __syncthreads();

  int buf = 0;
#pragma unroll
  for (int c = 0; c < 16; ++c) {
    if (c < 15) OSTAGE(c + 1, buf ^ 1);   // async, lands before barrier
    const int k0 = c * 32;
    const short* bb = sb + buf * 4096;
    bf16x8 af = *(const bf16x8*)(ay + k0);
#pragma unroll
    for (int ct = 0; ct < 4; ++ct) {
      const int roff = (wc * 64 + ct * 16 + col16) * 32 + quad * 8;
      bf16x8 bfr = *(const bf16x8*)(bb + roff);
      acc[ct] = MFMA16(af, bfr, acc[ct]);
    }
    __syncthreads();                     // drains in-flight stage + syncs
    buf ^= 1;
  }
#undef OSTAGE

#pragma unroll
  for (int ct = 0; ct < 4; ++ct) {
    const int col = tn * 128 + wc * 64 + ct * 16 + col16;
    const float bval = bo[col];
#pragma unroll
    for (int r = 0; r < 4; ++r) {
      const int row = tmb * 32 + wr * 16 + quad * 4 + r;
      out[(size_t)row * 512 + col] = acc[ct][r] + bval;
    }
  }
}

// ---------------------------------------------------------------------------
extern "C" void kernel_launch(void* const* d_in, const int* in_sizes, int n_in,
                              void* d_out, int out_size, void* d_ws, size_t ws_size,
                              hipStream_t stream)
{
  const float* x    = (const float*)d_in[0];
  const float* Wqkv = (const float*)d_in[1];
  const float* bqkv = (const float*)d_in[2];
  const float* Wo   = (const float*)d_in[3];
  const float* bo   = (const float*)d_in[4];
  float* out = (float*)d_out;

  // ws (ushort elems). Base (R6-proven, 54.0 MB): weights + q/k/v planes.
  ushort* wT_hi = (ushort*)d_ws;                    //  786432 (chunked layout)
  ushort* wT_lo = wT_hi + 786432;                   //  786432
  ushort* woT   = wT_lo + 786432;                   //  262144 (chunked layout)
  ushort* q_hi  = woT   + 262144;                   // 4194304 each below
  ushort* q_lo  = q_hi  + 4194304;
  ushort* k_hi  = q_lo  + 4194304;
  ushort* k_lo  = k_hi  + 4194304;
  ushort* v_nat = k_lo  + 4194304;
  ushort* tail  = v_nat + 4194304;

  // Roomy path (62.4 MB): xh/xl planes; vT aliases xh, y aliases xl (both
  // dead after K1). ws_size is launch-invariant -> stable graph capture.
  const bool roomy = ws_size >= 62390272ULL;
  ushort *xh, *xl, *vT, *y;
  if (roomy) {
    xh = tail; xl = tail + 4194304;
    vT = xh;   y  = xl;                 // reused post-K1
  } else {
    xh = xl = nullptr;
    vT = tail; y = v_nat;               // R6 mapping (54.0 MB, proven)
  }

  if (roomy) {
    cvt_k<true><<<4352, 256, 0, stream>>>(Wqkv, Wo, x, wT_hi, wT_lo, woT, xh, xl);
    qkv_gemm_k<true><<<768, 256, 0, stream>>>(x, xh, xl, wT_hi, wT_lo, bqkv,
                                              q_hi, q_lo, k_hi, k_lo, v_nat);
  } else {
    cvt_k<false><<<256, 256, 0, stream>>>(Wqkv, Wo, x, wT_hi, wT_lo, woT,
                                          nullptr, nullptr);
    qkv_gemm_k<false><<<768, 256, 0, stream>>>(x, nullptr, nullptr, wT_hi, wT_lo,
                                               bqkv, q_hi, q_lo, k_hi, k_lo, v_nat);
  }
  vtrans_k<<<1024, 256, 0, stream>>>(v_nat, vT);
  attn_k<<<512, 512, 0, stream>>>(q_hi, q_lo, k_hi, k_lo, vT, y);
  out_gemm_k<<<1024, 256, 0, stream>>>(y, woT, bo, out);
}